// Round 5
// baseline (451.993 us; speedup 1.0000x reference)
//
#include <hip/hip_runtime.h>
#include <hip/hip_bf16.h>

#define N_NODES 50000
#define N_EDGES 800000
#define HID 128

typedef __attribute__((ext_vector_type(8))) short short8;     // 8 bf16 (4 VGPR)
typedef __attribute__((ext_vector_type(4))) float f32x4;      // MFMA acc
typedef __attribute__((ext_vector_type(4))) unsigned short us4;

__device__ __forceinline__ unsigned short f2bf(float v) {
    union { float f; unsigned u; } x; x.f = v;
    unsigned r = x.u + 0x7fff + ((x.u >> 16) & 1);   // RTN-even
    return (unsigned short)(r >> 16);
}
__device__ __forceinline__ float bf2f(unsigned short b) {
    union { unsigned u; float f; } x; x.u = ((unsigned)b) << 16;
    return x.f;
}

// ---------------------------------------------------------------- utilities

__global__ void zero_k(int* __restrict__ p, int n) {
    int i = blockIdx.x * blockDim.x + threadIdx.x;
    if (i < n) p[i] = 0;
}

// count + per-edge rank (the atomic's return value) in one pass
__global__ void count_k(const int* __restrict__ dst, int* __restrict__ cnt,
                        int* __restrict__ rank, int E) {
    int e = blockIdx.x * blockDim.x + threadIdx.x;
    if (e < E) rank[e] = atomicAdd(&cnt[dst[e]], 1);
}

// ---------------- 3-pass multi-block exclusive scan over n counts ----------
#define SCAN_CHUNK 1024

__global__ __launch_bounds__(256)
void scan1_k(const int* __restrict__ cnt, int* __restrict__ bsum, int n) {
    const int t = threadIdx.x;
    const int base = blockIdx.x * SCAN_CHUNK + t * 4;
    int4 v = {0, 0, 0, 0};
    if (base + 3 < n) v = *(const int4*)&cnt[base];
    else {
        if (base + 0 < n) v.x = cnt[base + 0];
        if (base + 1 < n) v.y = cnt[base + 1];
        if (base + 2 < n) v.z = cnt[base + 2];
        if (base + 3 < n) v.w = cnt[base + 3];
    }
    int s = v.x + v.y + v.z + v.w;
    __shared__ int sh[256];
    sh[t] = s;
    __syncthreads();
    for (int o = 128; o > 0; o >>= 1) {
        if (t < o) sh[t] += sh[t + o];
        __syncthreads();
    }
    if (t == 0) bsum[blockIdx.x] = sh[0];
}

__global__ __launch_bounds__(64)
void scan2_k(int* __restrict__ bsum, int* __restrict__ offs, int B, int n) {
    const int t = threadIdx.x;
    int own = (t < B) ? bsum[t] : 0;
    int v = own;
    for (int o = 1; o < 64; o <<= 1) {
        int u = __shfl_up(v, o, 64);
        if (t >= o) v += u;
    }
    if (t < B) bsum[t] = v - own;
    if (t == 63) offs[n] = v;
}

__global__ __launch_bounds__(256)
void scan3_k(const int* __restrict__ cnt, const int* __restrict__ bsum,
             int* __restrict__ offs, int n) {
    const int t = threadIdx.x;
    const int base = blockIdx.x * SCAN_CHUNK + t * 4;
    int4 v = {0, 0, 0, 0};
    if (base + 3 < n) v = *(const int4*)&cnt[base];
    else {
        if (base + 0 < n) v.x = cnt[base + 0];
        if (base + 1 < n) v.y = cnt[base + 1];
        if (base + 2 < n) v.z = cnt[base + 2];
        if (base + 3 < n) v.w = cnt[base + 3];
    }
    int s = v.x + v.y + v.z + v.w;
    __shared__ int sh[256];
    sh[t] = s;
    __syncthreads();
    for (int o = 1; o < 256; o <<= 1) {
        int u = (t >= o) ? sh[t - o] : 0;
        __syncthreads();
        sh[t] += u;
        __syncthreads();
    }
    int excl = ((t == 0) ? 0 : sh[t - 1]) + bsum[blockIdx.x];
    int4 o4;
    o4.x = excl;
    o4.y = o4.x + v.x;
    o4.z = o4.y + v.y;
    o4.w = o4.z + v.z;
    if (base + 3 < n) {
        *(int4*)&offs[base] = o4;
    } else {
        if (base + 0 < n) offs[base + 0] = o4.x;
        if (base + 1 < n) offs[base + 1] = o4.y;
        if (base + 2 < n) offs[base + 2] = o4.z;
        if (base + 3 < n) offs[base + 3] = o4.w;
    }
}

// atomic-free fill: coalesced reads of dst/rank/src, one random write
__global__ void fill2_k(const int* __restrict__ src, const int* __restrict__ dst,
                        const int* __restrict__ rank, const int* __restrict__ offs,
                        int* __restrict__ csr, int E) {
    int e = blockIdx.x * blockDim.x + threadIdx.x;
    if (e < E) csr[offs[dst[e]] + rank[e]] = src[e];
}

// ------------------------------------------- weight pre-split (bf16 hi/lo)
// Transposed bf16 hi/lo: Wt[n][k], slot stride 16384 elems.
// Slots: 2l = W_a[l], 2l+1 = W_b[l] (l=0..2), 6 = W_h1.
__global__ __launch_bounds__(256)
void wcvt_k(const float* __restrict__ Wa, const float* __restrict__ Wb,
            const float* __restrict__ Wh1,
            unsigned short* __restrict__ whi, unsigned short* __restrict__ wlo) {
    int id = blockIdx.x * 256 + threadIdx.x;
    float v; int dst;
    if (id < 49152) {                      // 3 x 128x128 W_a
        int l = id >> 14, e = id & 16383;
        v = Wa[id];
        int n = e & 127, k = e >> 7;
        dst = (2 * l) * 16384 + n * 128 + k;
    } else if (id < 98304) {               // 3 x 128x128 W_b
        int id2 = id - 49152;
        int l = id2 >> 14, e = id2 & 16383;
        v = Wb[id2];
        int n = e & 127, k = e >> 7;
        dst = (2 * l + 1) * 16384 + n * 128 + k;
    } else if (id < 106496) {              // 128x64 W_h1
        int e = id - 98304;
        v = Wh1[e];
        int n = e & 63, k = e >> 6;
        dst = 6 * 16384 + n * 128 + k;
    } else return;
    unsigned short hi = f2bf(v);
    whi[dst] = hi;
    wlo[dst] = f2bf(v - bf2f(hi));
}

// ------------------------------------------------------- fused GIN layer
// One block = 32 nodes (grid 1563 -> ~6 blocks/CU co-resident; gather of one
// block overlaps MFMA of another). LDS = 2 x 32 x 136 shorts = 17.4 KB.
// Phase 1: CSR gather -> LDS bf16 hi/lo. Phase 2: z @ W_a (+b, ReLU).
// Phase 3: u @ W_b (+b, ReLU) -> global; HEAD adds W_h1 + 64->2 head.
// MFMA 16x16x32 layouts (verified R3): A[m=lane&15][k=quad*8+j],
// B = Wt[n=lane&15][k], C/D col=lane&15 row=quad*4+reg.
template <bool HEAD>
__global__ __launch_bounds__(256, 6)
void fused_layer_k(const float* __restrict__ h_in,
                   const int* __restrict__ offs, const int* __restrict__ csr,
                   const float* __restrict__ eps, int layer,
                   const unsigned short* __restrict__ WAhi, const unsigned short* __restrict__ WAlo,
                   const float* __restrict__ ba,
                   const unsigned short* __restrict__ WBhi, const unsigned short* __restrict__ WBlo,
                   const float* __restrict__ bb,
                   const unsigned short* __restrict__ WHhi, const unsigned short* __restrict__ WHlo,
                   const float* __restrict__ bh1,
                   const float* __restrict__ W2, const float* __restrict__ b2,
                   float* __restrict__ outp) {
    __shared__ unsigned short Zhi[32 * 136];   // 8,704 B
    __shared__ unsigned short Zlo[32 * 136];
    const int t = threadIdx.x;
    const int wave = t >> 6, lane = t & 63;
    const int m = lane & 15, quad = lane >> 4;
    const int row0 = blockIdx.x * 32;
    const float sc = 1.0f + eps[layer];

    // ---------- phase 1: gather-aggregate -> LDS bf16 hi/lo
    {
        const int half = lane >> 5, l32 = lane & 31;
        const float4* __restrict__ h4 = (const float4*)h_in;
        for (int p4 = 0; p4 < 4; ++p4) {
            const int r = wave * 8 + p4 * 2 + half;
            const int node = row0 + r;
            float4 o = {0, 0, 0, 0};
            if (node < N_NODES) {
                const int beg = offs[node], end = offs[node + 1];
                float4 a0 = {0,0,0,0}, a1 = {0,0,0,0}, a2 = {0,0,0,0}, a3 = {0,0,0,0};
                int j = beg;
                for (; j + 4 <= end; j += 4) {
                    int s0 = csr[j], s1 = csr[j+1], s2 = csr[j+2], s3 = csr[j+3];
                    float4 v0 = h4[(size_t)s0 * 32 + l32];
                    float4 v1 = h4[(size_t)s1 * 32 + l32];
                    float4 v2 = h4[(size_t)s2 * 32 + l32];
                    float4 v3 = h4[(size_t)s3 * 32 + l32];
                    a0.x += v0.x; a0.y += v0.y; a0.z += v0.z; a0.w += v0.w;
                    a1.x += v1.x; a1.y += v1.y; a1.z += v1.z; a1.w += v1.w;
                    a2.x += v2.x; a2.y += v2.y; a2.z += v2.z; a2.w += v2.w;
                    a3.x += v3.x; a3.y += v3.y; a3.z += v3.z; a3.w += v3.w;
                }
                for (; j < end; ++j) {
                    float4 v = h4[(size_t)csr[j] * 32 + l32];
                    a0.x += v.x; a0.y += v.y; a0.z += v.z; a0.w += v.w;
                }
                float4 self = h4[(size_t)node * 32 + l32];
                o.x = sc * self.x + ((a0.x + a1.x) + (a2.x + a3.x));
                o.y = sc * self.y + ((a0.y + a1.y) + (a2.y + a3.y));
                o.z = sc * self.z + ((a0.z + a1.z) + (a2.z + a3.z));
                o.w = sc * self.w + ((a0.w + a1.w) + (a2.w + a3.w));
            }
            us4 hi, lo;
            hi.x = f2bf(o.x); lo.x = f2bf(o.x - bf2f(hi.x));
            hi.y = f2bf(o.y); lo.y = f2bf(o.y - bf2f(hi.y));
            hi.z = f2bf(o.z); lo.z = f2bf(o.z - bf2f(hi.z));
            hi.w = f2bf(o.w); lo.w = f2bf(o.w - bf2f(hi.w));
            *(us4*)&Zhi[r * 136 + l32 * 4] = hi;
            *(us4*)&Zlo[r * 136 + l32 * 4] = lo;
        }
    }

    // ---------- W_a fragments (cols: wave*32 + ct*16 + m)
    short8 wh[2][4], wl[2][4];
    for (int ct = 0; ct < 2; ++ct) {
        int n = wave * 32 + ct * 16 + m;
        for (int ks = 0; ks < 4; ++ks) {
            wh[ct][ks] = *(const short8*)&WAhi[n * 128 + ks * 32 + quad * 8];
            wl[ct][ks] = *(const short8*)&WAlo[n * 128 + ks * 32 + quad * 8];
        }
    }
    __syncthreads();

    // ---------- phase 2: z @ W_a   (2 row-strips of 16)
    f32x4 acc[2][2];
    for (int s = 0; s < 2; ++s)
        for (int ct = 0; ct < 2; ++ct) acc[s][ct] = (f32x4){0, 0, 0, 0};
    for (int s = 0; s < 2; ++s) {
        const int r = s * 16 + m;
        for (int ks = 0; ks < 4; ++ks) {
            short8 zh = *(const short8*)&Zhi[r * 136 + ks * 32 + quad * 8];
            short8 zl = *(const short8*)&Zlo[r * 136 + ks * 32 + quad * 8];
            for (int ct = 0; ct < 2; ++ct) {
                acc[s][ct] = __builtin_amdgcn_mfma_f32_16x16x32_bf16(zh, wh[ct][ks], acc[s][ct], 0, 0, 0);
                acc[s][ct] = __builtin_amdgcn_mfma_f32_16x16x32_bf16(zh, wl[ct][ks], acc[s][ct], 0, 0, 0);
                acc[s][ct] = __builtin_amdgcn_mfma_f32_16x16x32_bf16(zl, wh[ct][ks], acc[s][ct], 0, 0, 0);
            }
        }
    }

    // ---------- W_b fragments
    for (int ct = 0; ct < 2; ++ct) {
        int n = wave * 32 + ct * 16 + m;
        for (int ks = 0; ks < 4; ++ks) {
            wh[ct][ks] = *(const short8*)&WBhi[n * 128 + ks * 32 + quad * 8];
            wl[ct][ks] = *(const short8*)&WBlo[n * 128 + ks * 32 + quad * 8];
        }
    }
    __syncthreads();   // all z reads done; safe to overwrite LDS

    // ---------- u = relu(acc + ba) -> LDS bf16 hi/lo
    for (int s = 0; s < 2; ++s) {
        for (int ct = 0; ct < 2; ++ct) {
            int c = wave * 32 + ct * 16 + m;
            float bac = ba[c];
            for (int i = 0; i < 4; ++i) {
                int r = s * 16 + quad * 4 + i;
                float v = fmaxf(acc[s][ct][i] + bac, 0.0f);
                unsigned short hv = f2bf(v);
                Zhi[r * 136 + c] = hv;
                Zlo[r * 136 + c] = f2bf(v - bf2f(hv));
            }
        }
    }
    __syncthreads();

    // ---------- phase 3: u @ W_b
    for (int s = 0; s < 2; ++s)
        for (int ct = 0; ct < 2; ++ct) acc[s][ct] = (f32x4){0, 0, 0, 0};
    for (int s = 0; s < 2; ++s) {
        const int r = s * 16 + m;
        for (int ks = 0; ks < 4; ++ks) {
            short8 zh = *(const short8*)&Zhi[r * 136 + ks * 32 + quad * 8];
            short8 zl = *(const short8*)&Zlo[r * 136 + ks * 32 + quad * 8];
            for (int ct = 0; ct < 2; ++ct) {
                acc[s][ct] = __builtin_amdgcn_mfma_f32_16x16x32_bf16(zh, wh[ct][ks], acc[s][ct], 0, 0, 0);
                acc[s][ct] = __builtin_amdgcn_mfma_f32_16x16x32_bf16(zh, wl[ct][ks], acc[s][ct], 0, 0, 0);
                acc[s][ct] = __builtin_amdgcn_mfma_f32_16x16x32_bf16(zl, wh[ct][ks], acc[s][ct], 0, 0, 0);
            }
        }
    }

    if (!HEAD) {
        // ---------- h = relu(acc + bb) -> fp32 global
        for (int s = 0; s < 2; ++s) {
            for (int ct = 0; ct < 2; ++ct) {
                int c = wave * 32 + ct * 16 + m;
                float bbc = bb[c];
                for (int i = 0; i < 4; ++i) {
                    int row = row0 + s * 16 + quad * 4 + i;
                    if (row < N_NODES)
                        outp[(size_t)row * 128 + c] = fmaxf(acc[s][ct][i] + bbc, 0.0f);
                }
            }
        }
    } else {
        // ---------- W_h1 fragments (64 cols: wave*16 + m)
        short8 hh[4], hl[4];
        {
            int n = wave * 16 + m;
            for (int ks = 0; ks < 4; ++ks) {
                hh[ks] = *(const short8*)&WHhi[n * 128 + ks * 32 + quad * 8];
                hl[ks] = *(const short8*)&WHlo[n * 128 + ks * 32 + quad * 8];
            }
        }
        __syncthreads();   // all u reads done

        // ---------- h = relu(acc + bb) -> LDS bf16 hi/lo
        for (int s = 0; s < 2; ++s) {
            for (int ct = 0; ct < 2; ++ct) {
                int c = wave * 32 + ct * 16 + m;
                float bbc = bb[c];
                for (int i = 0; i < 4; ++i) {
                    int r = s * 16 + quad * 4 + i;
                    float v = fmaxf(acc[s][ct][i] + bbc, 0.0f);
                    unsigned short hv = f2bf(v);
                    Zhi[r * 136 + c] = hv;
                    Zlo[r * 136 + c] = f2bf(v - bf2f(hv));
                }
            }
        }
        __syncthreads();

        // ---------- phase 4: h @ W_h1 (128 -> 64)
        f32x4 a3[2];
        for (int s = 0; s < 2; ++s) a3[s] = (f32x4){0, 0, 0, 0};
        for (int s = 0; s < 2; ++s) {
            const int r = s * 16 + m;
            for (int ks = 0; ks < 4; ++ks) {
                short8 zh = *(const short8*)&Zhi[r * 136 + ks * 32 + quad * 8];
                short8 zl = *(const short8*)&Zlo[r * 136 + ks * 32 + quad * 8];
                a3[s] = __builtin_amdgcn_mfma_f32_16x16x32_bf16(zh, hh[ks], a3[s], 0, 0, 0);
                a3[s] = __builtin_amdgcn_mfma_f32_16x16x32_bf16(zh, hl[ks], a3[s], 0, 0, 0);
                a3[s] = __builtin_amdgcn_mfma_f32_16x16x32_bf16(zl, hh[ks], a3[s], 0, 0, 0);
            }
        }
        __syncthreads();   // phase-4 reads done; reuse LDS as fp32

        float* Hid = (float*)Zhi;   // 32 x 68 fp32 = 8,704 B (fits in Zhi)
        for (int s = 0; s < 2; ++s) {
            int c = wave * 16 + m;
            float bc = bh1[c];
            for (int i = 0; i < 4; ++i) {
                int r = s * 16 + quad * 4 + i;
                Hid[r * 68 + c] = fmaxf(a3[s][i] + bc, 0.0f);
            }
        }
        __syncthreads();

        // ---------- phase 5: hid @ W_h2 (64 -> 2) + b2 -> out
        if (t < 64) {
            int r = t >> 1, col = t & 1;
            float a = b2[col];
#pragma unroll
            for (int j = 0; j < 64; ++j) a += Hid[r * 68 + j] * W2[j * 2 + col];
            int node = row0 + r;
            if (node < N_NODES) outp[(size_t)node * 2 + col] = a;
        }
    }
}

// ------------------------------------------------------------------ launch

extern "C" void kernel_launch(void* const* d_in, const int* in_sizes, int n_in,
                              void* d_out, int out_size, void* d_ws, size_t ws_size,
                              hipStream_t stream) {
    const float* x    = (const float*)d_in[0];
    const int*   ei   = (const int*)d_in[1];
    const float* eps  = (const float*)d_in[2];
    const float* W_a  = (const float*)d_in[3];
    const float* b_a  = (const float*)d_in[4];
    const float* W_b  = (const float*)d_in[5];
    const float* b_b  = (const float*)d_in[6];
    const float* W_h1 = (const float*)d_in[7];
    const float* b_h1 = (const float*)d_in[8];
    const float* W_h2 = (const float*)d_in[9];
    const float* b_h2 = (const float*)d_in[10];
    float* out = (float*)d_out;

    const int N = N_NODES, E = N_EDGES;
    const int* src = ei;
    const int* dst = ei + E;

    char* ws = (char*)d_ws;
    size_t off = 0;
    auto carve = [&](size_t bytes) {
        char* p = ws + off;
        off = (off + bytes + 255) & ~(size_t)255;
        return p;
    };
    float* bufA   = (float*)carve((size_t)N * HID * sizeof(float));
    float* bufB   = (float*)carve((size_t)N * HID * sizeof(float));
    int*   cnt    = (int*)carve((size_t)N * sizeof(int));
    int*   offs   = (int*)carve((size_t)(N + 1) * sizeof(int));
    int*   rank   = (int*)carve((size_t)E * sizeof(int));
    int*   csr    = (int*)carve((size_t)E * sizeof(int));
    int*   bsum   = (int*)carve(64 * sizeof(int));
    unsigned short* whi = (unsigned short*)carve(7 * 16384 * sizeof(unsigned short));
    unsigned short* wlo = (unsigned short*)carve(7 * 16384 * sizeof(unsigned short));
    (void)ws_size;

    // ---- CSR build (rank trick: no atomics in fill)
    zero_k<<<(N + 255) / 256, 256, 0, stream>>>(cnt, N);
    count_k<<<(E + 255) / 256, 256, 0, stream>>>(dst, cnt, rank, E);
    const int SB = (N + SCAN_CHUNK - 1) / SCAN_CHUNK;
    scan1_k<<<SB, 256, 0, stream>>>(cnt, bsum, N);
    scan2_k<<<1, 64, 0, stream>>>(bsum, offs, SB, N);
    scan3_k<<<SB, 256, 0, stream>>>(cnt, bsum, offs, N);
    fill2_k<<<(E + 255) / 256, 256, 0, stream>>>(src, dst, rank, offs, csr, E);

    // ---- weight split/transpose
    wcvt_k<<<(106496 + 255) / 256, 256, 0, stream>>>(W_a, W_b, W_h1, whi, wlo);

    const int grid = (N + 31) / 32;
    #define WSLOT(s) (whi + (s) * 16384), (wlo + (s) * 16384)

    fused_layer_k<false><<<grid, 256, 0, stream>>>(
        x, offs, csr, eps, 0,
        WSLOT(0), b_a + 0 * 128, WSLOT(1), b_b + 0 * 128,
        (const unsigned short*)nullptr, (const unsigned short*)nullptr,
        (const float*)nullptr, (const float*)nullptr, (const float*)nullptr, bufA);
    fused_layer_k<false><<<grid, 256, 0, stream>>>(
        bufA, offs, csr, eps, 1,
        WSLOT(2), b_a + 1 * 128, WSLOT(3), b_b + 1 * 128,
        (const unsigned short*)nullptr, (const unsigned short*)nullptr,
        (const float*)nullptr, (const float*)nullptr, (const float*)nullptr, bufB);
    fused_layer_k<true><<<grid, 256, 0, stream>>>(
        bufB, offs, csr, eps, 2,
        WSLOT(4), b_a + 2 * 128, WSLOT(5), b_b + 2 * 128,
        WSLOT(6), b_h1, W_h2, b_h2, out);
}

// Round 6
// 407.265 us; speedup vs baseline: 1.1098x; 1.1098x over previous
//
#include <hip/hip_runtime.h>
#include <hip/hip_bf16.h>

#define N_NODES 50000
#define N_EDGES 800000
#define HID 128

typedef __attribute__((ext_vector_type(8))) short short8;     // 8 bf16 (4 VGPR)
typedef __attribute__((ext_vector_type(4))) float f32x4;      // MFMA acc
typedef __attribute__((ext_vector_type(4))) unsigned short us4;
typedef _Float16 hv4 __attribute__((ext_vector_type(4)));     // 4 fp16 (8 B)

__device__ __forceinline__ unsigned short f2bf(float v) {
    union { float f; unsigned u; } x; x.f = v;
    unsigned r = x.u + 0x7fff + ((x.u >> 16) & 1);   // RTN-even
    return (unsigned short)(r >> 16);
}
__device__ __forceinline__ float bf2f(unsigned short b) {
    union { unsigned u; float f; } x; x.u = ((unsigned)b) << 16;
    return x.f;
}

// ---------------------------------------------------------------- utilities

__global__ void zero_k(int* __restrict__ p, int n) {
    int i = blockIdx.x * blockDim.x + threadIdx.x;
    if (i < n) p[i] = 0;
}

// count + per-edge rank (the atomic's return value) in one pass
__global__ void count_k(const int* __restrict__ dst, int* __restrict__ cnt,
                        int* __restrict__ rank, int E) {
    int e = blockIdx.x * blockDim.x + threadIdx.x;
    if (e < E) rank[e] = atomicAdd(&cnt[dst[e]], 1);
}

// ---------------- 3-pass multi-block exclusive scan over n counts ----------
#define SCAN_CHUNK 1024

__global__ __launch_bounds__(256)
void scan1_k(const int* __restrict__ cnt, int* __restrict__ bsum, int n) {
    const int t = threadIdx.x;
    const int base = blockIdx.x * SCAN_CHUNK + t * 4;
    int4 v = {0, 0, 0, 0};
    if (base + 3 < n) v = *(const int4*)&cnt[base];
    else {
        if (base + 0 < n) v.x = cnt[base + 0];
        if (base + 1 < n) v.y = cnt[base + 1];
        if (base + 2 < n) v.z = cnt[base + 2];
        if (base + 3 < n) v.w = cnt[base + 3];
    }
    int s = v.x + v.y + v.z + v.w;
    __shared__ int sh[256];
    sh[t] = s;
    __syncthreads();
    for (int o = 128; o > 0; o >>= 1) {
        if (t < o) sh[t] += sh[t + o];
        __syncthreads();
    }
    if (t == 0) bsum[blockIdx.x] = sh[0];
}

__global__ __launch_bounds__(64)
void scan2_k(int* __restrict__ bsum, int* __restrict__ offs, int B, int n) {
    const int t = threadIdx.x;
    int own = (t < B) ? bsum[t] : 0;
    int v = own;
    for (int o = 1; o < 64; o <<= 1) {
        int u = __shfl_up(v, o, 64);
        if (t >= o) v += u;
    }
    if (t < B) bsum[t] = v - own;
    if (t == 63) offs[n] = v;
}

__global__ __launch_bounds__(256)
void scan3_k(const int* __restrict__ cnt, const int* __restrict__ bsum,
             int* __restrict__ offs, int n) {
    const int t = threadIdx.x;
    const int base = blockIdx.x * SCAN_CHUNK + t * 4;
    int4 v = {0, 0, 0, 0};
    if (base + 3 < n) v = *(const int4*)&cnt[base];
    else {
        if (base + 0 < n) v.x = cnt[base + 0];
        if (base + 1 < n) v.y = cnt[base + 1];
        if (base + 2 < n) v.z = cnt[base + 2];
        if (base + 3 < n) v.w = cnt[base + 3];
    }
    int s = v.x + v.y + v.z + v.w;
    __shared__ int sh[256];
    sh[t] = s;
    __syncthreads();
    for (int o = 1; o < 256; o <<= 1) {
        int u = (t >= o) ? sh[t - o] : 0;
        __syncthreads();
        sh[t] += u;
        __syncthreads();
    }
    int excl = ((t == 0) ? 0 : sh[t - 1]) + bsum[blockIdx.x];
    int4 o4;
    o4.x = excl;
    o4.y = o4.x + v.x;
    o4.z = o4.y + v.y;
    o4.w = o4.z + v.z;
    if (base + 3 < n) {
        *(int4*)&offs[base] = o4;
    } else {
        if (base + 0 < n) offs[base + 0] = o4.x;
        if (base + 1 < n) offs[base + 1] = o4.y;
        if (base + 2 < n) offs[base + 2] = o4.z;
        if (base + 3 < n) offs[base + 3] = o4.w;
    }
}

// atomic-free fill: coalesced reads of dst/rank/src, one random write
__global__ void fill2_k(const int* __restrict__ src, const int* __restrict__ dst,
                        const int* __restrict__ rank, const int* __restrict__ offs,
                        int* __restrict__ csr, int E) {
    int e = blockIdx.x * blockDim.x + threadIdx.x;
    if (e < E) csr[offs[dst[e]] + rank[e]] = src[e];
}

// --------------------------------------------------- x -> fp16 table
__global__ __launch_bounds__(256)
void xcvt_k(const float* __restrict__ x, _Float16* __restrict__ xh, int n4) {
    int i = blockIdx.x * 256 + threadIdx.x;
    if (i < n4) {
        float4 v = *(const float4*)&x[i * 4];
        hv4 o;
        o.x = (_Float16)v.x; o.y = (_Float16)v.y;
        o.z = (_Float16)v.z; o.w = (_Float16)v.w;
        *(hv4*)&xh[i * 4] = o;
    }
}

// ------------------------------------------- weight pre-split (bf16 hi/lo)
// Transposed bf16 hi/lo: Wt[n][k], slot stride 16384 elems.
// Slots: 2l = W_a[l], 2l+1 = W_b[l] (l=0..2), 6 = W_h1.
__global__ __launch_bounds__(256)
void wcvt_k(const float* __restrict__ Wa, const float* __restrict__ Wb,
            const float* __restrict__ Wh1,
            unsigned short* __restrict__ whi, unsigned short* __restrict__ wlo) {
    int id = blockIdx.x * 256 + threadIdx.x;
    float v; int dst;
    if (id < 49152) {                      // 3 x 128x128 W_a
        int l = id >> 14, e = id & 16383;
        v = Wa[id];
        int n = e & 127, k = e >> 7;
        dst = (2 * l) * 16384 + n * 128 + k;
    } else if (id < 98304) {               // 3 x 128x128 W_b
        int id2 = id - 49152;
        int l = id2 >> 14, e = id2 & 16383;
        v = Wb[id2];
        int n = e & 127, k = e >> 7;
        dst = (2 * l + 1) * 16384 + n * 128 + k;
    } else if (id < 106496) {              // 128x64 W_h1
        int e = id - 98304;
        v = Wh1[e];
        int n = e & 63, k = e >> 6;
        dst = 6 * 16384 + n * 128 + k;
    } else return;
    unsigned short hi = f2bf(v);
    whi[dst] = hi;
    wlo[dst] = f2bf(v - bf2f(hi));
}

// ------------------------------------------------------- fused GIN layer
// One block = 32 nodes. h tables are fp16 (256 B rows): halves the L2-miss
// gather traffic that R5 counters showed as the binding ~2.2 TB/s ceiling.
// Phase 1: CSR gather (fp16 rows, fp32 accum) -> LDS bf16 hi/lo.
// Phase 2: z @ W_a (+b, ReLU). Phase 3: u @ W_b (+b, ReLU) -> fp16 global;
// HEAD variant continues through W_h1 and the 64->2 head -> fp32 out.
// MFMA 16x16x32 layouts (verified R3): A[m=lane&15][k=quad*8+j],
// B = Wt[n=lane&15][k], C/D col=lane&15 row=quad*4+reg.
template <bool HEAD>
__global__ __launch_bounds__(256, 6)
void fused_layer_k(const _Float16* __restrict__ h_in,
                   const int* __restrict__ offs, const int* __restrict__ csr,
                   const float* __restrict__ eps, int layer,
                   const unsigned short* __restrict__ WAhi, const unsigned short* __restrict__ WAlo,
                   const float* __restrict__ ba,
                   const unsigned short* __restrict__ WBhi, const unsigned short* __restrict__ WBlo,
                   const float* __restrict__ bb,
                   const unsigned short* __restrict__ WHhi, const unsigned short* __restrict__ WHlo,
                   const float* __restrict__ bh1,
                   const float* __restrict__ W2, const float* __restrict__ b2,
                   void* __restrict__ outp) {
    __shared__ unsigned short Zhi[32 * 136];   // 8,704 B
    __shared__ unsigned short Zlo[32 * 136];
    const int t = threadIdx.x;
    const int wave = t >> 6, lane = t & 63;
    const int m = lane & 15, quad = lane >> 4;
    const int row0 = blockIdx.x * 32;
    const float sc = 1.0f + eps[layer];

    // ---------- phase 1: gather-aggregate (fp16 rows) -> LDS bf16 hi/lo
    {
        const int hf = lane >> 5, l32 = lane & 31;
        const hv4* __restrict__ h4 = (const hv4*)h_in;   // row stride = 32 hv4
        for (int p4 = 0; p4 < 4; ++p4) {
            const int r = wave * 8 + p4 * 2 + hf;
            const int node = row0 + r;
            float4 o = {0, 0, 0, 0};
            if (node < N_NODES) {
                const int beg = offs[node], end = offs[node + 1];
                float4 a0 = {0,0,0,0}, a1 = {0,0,0,0}, a2 = {0,0,0,0}, a3 = {0,0,0,0};
                int j = beg;
                for (; j + 4 <= end; j += 4) {
                    int s0 = csr[j], s1 = csr[j+1], s2 = csr[j+2], s3 = csr[j+3];
                    hv4 v0 = h4[(size_t)s0 * 32 + l32];
                    hv4 v1 = h4[(size_t)s1 * 32 + l32];
                    hv4 v2 = h4[(size_t)s2 * 32 + l32];
                    hv4 v3 = h4[(size_t)s3 * 32 + l32];
                    a0.x += (float)v0.x; a0.y += (float)v0.y; a0.z += (float)v0.z; a0.w += (float)v0.w;
                    a1.x += (float)v1.x; a1.y += (float)v1.y; a1.z += (float)v1.z; a1.w += (float)v1.w;
                    a2.x += (float)v2.x; a2.y += (float)v2.y; a2.z += (float)v2.z; a2.w += (float)v2.w;
                    a3.x += (float)v3.x; a3.y += (float)v3.y; a3.z += (float)v3.z; a3.w += (float)v3.w;
                }
                for (; j < end; ++j) {
                    hv4 v = h4[(size_t)csr[j] * 32 + l32];
                    a0.x += (float)v.x; a0.y += (float)v.y; a0.z += (float)v.z; a0.w += (float)v.w;
                }
                hv4 self = h4[(size_t)node * 32 + l32];
                o.x = sc * (float)self.x + ((a0.x + a1.x) + (a2.x + a3.x));
                o.y = sc * (float)self.y + ((a0.y + a1.y) + (a2.y + a3.y));
                o.z = sc * (float)self.z + ((a0.z + a1.z) + (a2.z + a3.z));
                o.w = sc * (float)self.w + ((a0.w + a1.w) + (a2.w + a3.w));
            }
            us4 hi, lo;
            hi.x = f2bf(o.x); lo.x = f2bf(o.x - bf2f(hi.x));
            hi.y = f2bf(o.y); lo.y = f2bf(o.y - bf2f(hi.y));
            hi.z = f2bf(o.z); lo.z = f2bf(o.z - bf2f(hi.z));
            hi.w = f2bf(o.w); lo.w = f2bf(o.w - bf2f(hi.w));
            *(us4*)&Zhi[r * 136 + l32 * 4] = hi;
            *(us4*)&Zlo[r * 136 + l32 * 4] = lo;
        }
    }

    // ---------- W_a fragments (cols: wave*32 + ct*16 + m)
    short8 wh[2][4], wl[2][4];
    for (int ct = 0; ct < 2; ++ct) {
        int n = wave * 32 + ct * 16 + m;
        for (int ks = 0; ks < 4; ++ks) {
            wh[ct][ks] = *(const short8*)&WAhi[n * 128 + ks * 32 + quad * 8];
            wl[ct][ks] = *(const short8*)&WAlo[n * 128 + ks * 32 + quad * 8];
        }
    }
    __syncthreads();

    // ---------- phase 2: z @ W_a   (2 row-strips of 16)
    f32x4 acc[2][2];
    for (int s = 0; s < 2; ++s)
        for (int ct = 0; ct < 2; ++ct) acc[s][ct] = (f32x4){0, 0, 0, 0};
    for (int s = 0; s < 2; ++s) {
        const int r = s * 16 + m;
        for (int ks = 0; ks < 4; ++ks) {
            short8 zh = *(const short8*)&Zhi[r * 136 + ks * 32 + quad * 8];
            short8 zl = *(const short8*)&Zlo[r * 136 + ks * 32 + quad * 8];
            for (int ct = 0; ct < 2; ++ct) {
                acc[s][ct] = __builtin_amdgcn_mfma_f32_16x16x32_bf16(zh, wh[ct][ks], acc[s][ct], 0, 0, 0);
                acc[s][ct] = __builtin_amdgcn_mfma_f32_16x16x32_bf16(zh, wl[ct][ks], acc[s][ct], 0, 0, 0);
                acc[s][ct] = __builtin_amdgcn_mfma_f32_16x16x32_bf16(zl, wh[ct][ks], acc[s][ct], 0, 0, 0);
            }
        }
    }

    // ---------- W_b fragments
    for (int ct = 0; ct < 2; ++ct) {
        int n = wave * 32 + ct * 16 + m;
        for (int ks = 0; ks < 4; ++ks) {
            wh[ct][ks] = *(const short8*)&WBhi[n * 128 + ks * 32 + quad * 8];
            wl[ct][ks] = *(const short8*)&WBlo[n * 128 + ks * 32 + quad * 8];
        }
    }
    __syncthreads();   // all z reads done; safe to overwrite LDS

    // ---------- u = relu(acc + ba) -> LDS bf16 hi/lo
    for (int s = 0; s < 2; ++s) {
        for (int ct = 0; ct < 2; ++ct) {
            int c = wave * 32 + ct * 16 + m;
            float bac = ba[c];
            for (int i = 0; i < 4; ++i) {
                int r = s * 16 + quad * 4 + i;
                float v = fmaxf(acc[s][ct][i] + bac, 0.0f);
                unsigned short hv = f2bf(v);
                Zhi[r * 136 + c] = hv;
                Zlo[r * 136 + c] = f2bf(v - bf2f(hv));
            }
        }
    }
    __syncthreads();

    // ---------- phase 3: u @ W_b
    for (int s = 0; s < 2; ++s)
        for (int ct = 0; ct < 2; ++ct) acc[s][ct] = (f32x4){0, 0, 0, 0};
    for (int s = 0; s < 2; ++s) {
        const int r = s * 16 + m;
        for (int ks = 0; ks < 4; ++ks) {
            short8 zh = *(const short8*)&Zhi[r * 136 + ks * 32 + quad * 8];
            short8 zl = *(const short8*)&Zlo[r * 136 + ks * 32 + quad * 8];
            for (int ct = 0; ct < 2; ++ct) {
                acc[s][ct] = __builtin_amdgcn_mfma_f32_16x16x32_bf16(zh, wh[ct][ks], acc[s][ct], 0, 0, 0);
                acc[s][ct] = __builtin_amdgcn_mfma_f32_16x16x32_bf16(zh, wl[ct][ks], acc[s][ct], 0, 0, 0);
                acc[s][ct] = __builtin_amdgcn_mfma_f32_16x16x32_bf16(zl, wh[ct][ks], acc[s][ct], 0, 0, 0);
            }
        }
    }

    if (!HEAD) {
        // ---------- h = relu(acc + bb) -> fp16 global
        _Float16* hout = (_Float16*)outp;
        for (int s = 0; s < 2; ++s) {
            for (int ct = 0; ct < 2; ++ct) {
                int c = wave * 32 + ct * 16 + m;
                float bbc = bb[c];
                for (int i = 0; i < 4; ++i) {
                    int row = row0 + s * 16 + quad * 4 + i;
                    if (row < N_NODES)
                        hout[(size_t)row * 128 + c] = (_Float16)fmaxf(acc[s][ct][i] + bbc, 0.0f);
                }
            }
        }
    } else {
        // ---------- W_h1 fragments (64 cols: wave*16 + m)
        short8 hh[4], hl[4];
        {
            int n = wave * 16 + m;
            for (int ks = 0; ks < 4; ++ks) {
                hh[ks] = *(const short8*)&WHhi[n * 128 + ks * 32 + quad * 8];
                hl[ks] = *(const short8*)&WHlo[n * 128 + ks * 32 + quad * 8];
            }
        }
        __syncthreads();   // all u reads done

        // ---------- h = relu(acc + bb) -> LDS bf16 hi/lo
        for (int s = 0; s < 2; ++s) {
            for (int ct = 0; ct < 2; ++ct) {
                int c = wave * 32 + ct * 16 + m;
                float bbc = bb[c];
                for (int i = 0; i < 4; ++i) {
                    int r = s * 16 + quad * 4 + i;
                    float v = fmaxf(acc[s][ct][i] + bbc, 0.0f);
                    unsigned short hv = f2bf(v);
                    Zhi[r * 136 + c] = hv;
                    Zlo[r * 136 + c] = f2bf(v - bf2f(hv));
                }
            }
        }
        __syncthreads();

        // ---------- phase 4: h @ W_h1 (128 -> 64)
        f32x4 a3[2];
        for (int s = 0; s < 2; ++s) a3[s] = (f32x4){0, 0, 0, 0};
        for (int s = 0; s < 2; ++s) {
            const int r = s * 16 + m;
            for (int ks = 0; ks < 4; ++ks) {
                short8 zh = *(const short8*)&Zhi[r * 136 + ks * 32 + quad * 8];
                short8 zl = *(const short8*)&Zlo[r * 136 + ks * 32 + quad * 8];
                a3[s] = __builtin_amdgcn_mfma_f32_16x16x32_bf16(zh, hh[ks], a3[s], 0, 0, 0);
                a3[s] = __builtin_amdgcn_mfma_f32_16x16x32_bf16(zh, hl[ks], a3[s], 0, 0, 0);
                a3[s] = __builtin_amdgcn_mfma_f32_16x16x32_bf16(zl, hh[ks], a3[s], 0, 0, 0);
            }
        }
        __syncthreads();   // phase-4 reads done; reuse LDS as fp32

        float* Hid = (float*)Zhi;   // 32 x 68 fp32 = 8,704 B (fits in Zhi)
        for (int s = 0; s < 2; ++s) {
            int c = wave * 16 + m;
            float bc = bh1[c];
            for (int i = 0; i < 4; ++i) {
                int r = s * 16 + quad * 4 + i;
                Hid[r * 68 + c] = fmaxf(a3[s][i] + bc, 0.0f);
            }
        }
        __syncthreads();

        // ---------- phase 5: hid @ W_h2 (64 -> 2) + b2 -> out
        if (t < 64) {
            float* outF = (float*)outp;
            int r = t >> 1, col = t & 1;
            float a = b2[col];
#pragma unroll
            for (int j = 0; j < 64; ++j) a += Hid[r * 68 + j] * W2[j * 2 + col];
            int node = row0 + r;
            if (node < N_NODES) outF[(size_t)node * 2 + col] = a;
        }
    }
}

// ------------------------------------------------------------------ launch

extern "C" void kernel_launch(void* const* d_in, const int* in_sizes, int n_in,
                              void* d_out, int out_size, void* d_ws, size_t ws_size,
                              hipStream_t stream) {
    const float* x    = (const float*)d_in[0];
    const int*   ei   = (const int*)d_in[1];
    const float* eps  = (const float*)d_in[2];
    const float* W_a  = (const float*)d_in[3];
    const float* b_a  = (const float*)d_in[4];
    const float* W_b  = (const float*)d_in[5];
    const float* b_b  = (const float*)d_in[6];
    const float* W_h1 = (const float*)d_in[7];
    const float* b_h1 = (const float*)d_in[8];
    const float* W_h2 = (const float*)d_in[9];
    const float* b_h2 = (const float*)d_in[10];
    float* out = (float*)d_out;

    const int N = N_NODES, E = N_EDGES;
    const int* src = ei;
    const int* dst = ei + E;

    char* ws = (char*)d_ws;
    size_t off = 0;
    auto carve = [&](size_t bytes) {
        char* p = ws + off;
        off = (off + bytes + 255) & ~(size_t)255;
        return p;
    };
    _Float16* xh   = (_Float16*)carve((size_t)N * HID * sizeof(_Float16));
    _Float16* bufA = (_Float16*)carve((size_t)N * HID * sizeof(_Float16));
    _Float16* bufB = (_Float16*)carve((size_t)N * HID * sizeof(_Float16));
    int*   cnt    = (int*)carve((size_t)N * sizeof(int));
    int*   offs   = (int*)carve((size_t)(N + 1) * sizeof(int));
    int*   rank   = (int*)carve((size_t)E * sizeof(int));
    int*   csr    = (int*)carve((size_t)E * sizeof(int));
    int*   bsum   = (int*)carve(64 * sizeof(int));
    unsigned short* whi = (unsigned short*)carve(7 * 16384 * sizeof(unsigned short));
    unsigned short* wlo = (unsigned short*)carve(7 * 16384 * sizeof(unsigned short));
    (void)ws_size;

    // ---- CSR build (rank trick: no atomics in fill)
    zero_k<<<(N + 255) / 256, 256, 0, stream>>>(cnt, N);
    count_k<<<(E + 255) / 256, 256, 0, stream>>>(dst, cnt, rank, E);
    const int SB = (N + SCAN_CHUNK - 1) / SCAN_CHUNK;
    scan1_k<<<SB, 256, 0, stream>>>(cnt, bsum, N);
    scan2_k<<<1, 64, 0, stream>>>(bsum, offs, SB, N);
    scan3_k<<<SB, 256, 0, stream>>>(cnt, bsum, offs, N);
    fill2_k<<<(E + 255) / 256, 256, 0, stream>>>(src, dst, rank, offs, csr, E);

    // ---- input + weight conversion
    xcvt_k<<<(N * HID / 4 + 255) / 256, 256, 0, stream>>>(x, xh, N * HID / 4);
    wcvt_k<<<(106496 + 255) / 256, 256, 0, stream>>>(W_a, W_b, W_h1, whi, wlo);

    const int grid = (N + 31) / 32;
    #define WSLOT(s) (whi + (s) * 16384), (wlo + (s) * 16384)

    fused_layer_k<false><<<grid, 256, 0, stream>>>(
        xh, offs, csr, eps, 0,
        WSLOT(0), b_a + 0 * 128, WSLOT(1), b_b + 0 * 128,
        (const unsigned short*)nullptr, (const unsigned short*)nullptr,
        (const float*)nullptr, (const float*)nullptr, (const float*)nullptr, (void*)bufA);
    fused_layer_k<false><<<grid, 256, 0, stream>>>(
        bufA, offs, csr, eps, 1,
        WSLOT(2), b_a + 1 * 128, WSLOT(3), b_b + 1 * 128,
        (const unsigned short*)nullptr, (const unsigned short*)nullptr,
        (const float*)nullptr, (const float*)nullptr, (const float*)nullptr, (void*)bufB);
    fused_layer_k<true><<<grid, 256, 0, stream>>>(
        bufB, offs, csr, eps, 2,
        WSLOT(4), b_a + 2 * 128, WSLOT(5), b_b + 2 * 128,
        WSLOT(6), b_h1, W_h2, b_h2, (void*)out);
}

// Round 7
// 374.388 us; speedup vs baseline: 1.2073x; 1.0878x over previous
//
#include <hip/hip_runtime.h>
#include <hip/hip_bf16.h>

#define N_NODES 50000
#define N_EDGES 800000
#define HID 128

typedef __attribute__((ext_vector_type(8))) short short8;     // 8 bf16 (4 VGPR)
typedef __attribute__((ext_vector_type(4))) float f32x4;      // MFMA acc
typedef __attribute__((ext_vector_type(4))) unsigned short us4;
typedef _Float16 hv4 __attribute__((ext_vector_type(4)));     // 4 fp16 (8 B)
typedef _Float16 hv8 __attribute__((ext_vector_type(8)));     // 8 fp16 (16 B)

__device__ __forceinline__ unsigned short f2bf(float v) {
    union { float f; unsigned u; } x; x.f = v;
    unsigned r = x.u + 0x7fff + ((x.u >> 16) & 1);   // RTN-even
    return (unsigned short)(r >> 16);
}
__device__ __forceinline__ float bf2f(unsigned short b) {
    union { unsigned u; float f; } x; x.u = ((unsigned)b) << 16;
    return x.f;
}

// ---------------------------------------------------------------- utilities

// count + per-edge rank (the atomic's return value) in one pass
__global__ void count_k(const int* __restrict__ dst, int* __restrict__ cnt,
                        int* __restrict__ rank, int E) {
    int e = blockIdx.x * blockDim.x + threadIdx.x;
    if (e < E) rank[e] = atomicAdd(&cnt[dst[e]], 1);
}

// ---------------- 3-pass multi-block exclusive scan over n counts ----------
#define SCAN_CHUNK 1024

__global__ __launch_bounds__(256)
void scan1_k(const int* __restrict__ cnt, int* __restrict__ bsum, int n) {
    const int t = threadIdx.x;
    const int base = blockIdx.x * SCAN_CHUNK + t * 4;
    int4 v = {0, 0, 0, 0};
    if (base + 3 < n) v = *(const int4*)&cnt[base];
    else {
        if (base + 0 < n) v.x = cnt[base + 0];
        if (base + 1 < n) v.y = cnt[base + 1];
        if (base + 2 < n) v.z = cnt[base + 2];
        if (base + 3 < n) v.w = cnt[base + 3];
    }
    int s = v.x + v.y + v.z + v.w;
    __shared__ int sh[256];
    sh[t] = s;
    __syncthreads();
    for (int o = 128; o > 0; o >>= 1) {
        if (t < o) sh[t] += sh[t + o];
        __syncthreads();
    }
    if (t == 0) bsum[blockIdx.x] = sh[0];
}

__global__ __launch_bounds__(64)
void scan2_k(int* __restrict__ bsum, int* __restrict__ offs, int B, int n) {
    const int t = threadIdx.x;
    int own = (t < B) ? bsum[t] : 0;
    int v = own;
    for (int o = 1; o < 64; o <<= 1) {
        int u = __shfl_up(v, o, 64);
        if (t >= o) v += u;
    }
    if (t < B) bsum[t] = v - own;
    if (t == 63) offs[n] = v;
}

__global__ __launch_bounds__(256)
void scan3_k(const int* __restrict__ cnt, const int* __restrict__ bsum,
             int* __restrict__ offs, int n) {
    const int t = threadIdx.x;
    const int base = blockIdx.x * SCAN_CHUNK + t * 4;
    int4 v = {0, 0, 0, 0};
    if (base + 3 < n) v = *(const int4*)&cnt[base];
    else {
        if (base + 0 < n) v.x = cnt[base + 0];
        if (base + 1 < n) v.y = cnt[base + 1];
        if (base + 2 < n) v.z = cnt[base + 2];
        if (base + 3 < n) v.w = cnt[base + 3];
    }
    int s = v.x + v.y + v.z + v.w;
    __shared__ int sh[256];
    sh[t] = s;
    __syncthreads();
    for (int o = 1; o < 256; o <<= 1) {
        int u = (t >= o) ? sh[t - o] : 0;
        __syncthreads();
        sh[t] += u;
        __syncthreads();
    }
    int excl = ((t == 0) ? 0 : sh[t - 1]) + bsum[blockIdx.x];
    int4 o4;
    o4.x = excl;
    o4.y = o4.x + v.x;
    o4.z = o4.y + v.y;
    o4.w = o4.z + v.z;
    if (base + 3 < n) {
        *(int4*)&offs[base] = o4;
    } else {
        if (base + 0 < n) offs[base + 0] = o4.x;
        if (base + 1 < n) offs[base + 1] = o4.y;
        if (base + 2 < n) offs[base + 2] = o4.z;
        if (base + 3 < n) offs[base + 3] = o4.w;
    }
}

// atomic-free fill: coalesced reads of dst/rank/src, one random write
__global__ void fill2_k(const int* __restrict__ src, const int* __restrict__ dst,
                        const int* __restrict__ rank, const int* __restrict__ offs,
                        int* __restrict__ csr, int E) {
    int e = blockIdx.x * blockDim.x + threadIdx.x;
    if (e < E) csr[offs[dst[e]] + rank[e]] = src[e];
}

// --------------------------------------------------- x -> fp16 table
__global__ __launch_bounds__(256)
void xcvt_k(const float* __restrict__ x, _Float16* __restrict__ xh, int n4) {
    int i = blockIdx.x * 256 + threadIdx.x;
    if (i < n4) {
        float4 v = *(const float4*)&x[i * 4];
        hv4 o;
        o.x = (_Float16)v.x; o.y = (_Float16)v.y;
        o.z = (_Float16)v.z; o.w = (_Float16)v.w;
        *(hv4*)&xh[i * 4] = o;
    }
}

// ------------------------------------------- weight pre-split (bf16 hi/lo)
// Transposed bf16 hi/lo: Wt[n][k], slot stride 16384 elems.
// Slots: 2l = W_a[l], 2l+1 = W_b[l] (l=0..2), 6 = W_h1.
__global__ __launch_bounds__(256)
void wcvt_k(const float* __restrict__ Wa, const float* __restrict__ Wb,
            const float* __restrict__ Wh1,
            unsigned short* __restrict__ whi, unsigned short* __restrict__ wlo) {
    int id = blockIdx.x * 256 + threadIdx.x;
    float v; int dst;
    if (id < 49152) {                      // 3 x 128x128 W_a
        int l = id >> 14, e = id & 16383;
        v = Wa[id];
        int n = e & 127, k = e >> 7;
        dst = (2 * l) * 16384 + n * 128 + k;
    } else if (id < 98304) {               // 3 x 128x128 W_b
        int id2 = id - 49152;
        int l = id2 >> 14, e = id2 & 16383;
        v = Wb[id2];
        int n = e & 127, k = e >> 7;
        dst = (2 * l + 1) * 16384 + n * 128 + k;
    } else if (id < 106496) {              // 128x64 W_h1
        int e = id - 98304;
        v = Wh1[e];
        int n = e & 63, k = e >> 6;
        dst = 6 * 16384 + n * 128 + k;
    } else return;
    unsigned short hi = f2bf(v);
    whi[dst] = hi;
    wlo[dst] = f2bf(v - bf2f(hi));
}

// ------------------------------------------------------- fused GIN layer
// One block = 32 nodes. Gather: 16 lanes x 16 B (hv8) per fp16 row -> one
// wave-load fetches 4 rows (R6 fetched 2): halves the wave-load count the
// R3/R5/R6 data shows is the binding resource (time ~ requests/occupancy).
// Phase 1: CSR gather (fp16 rows, fp32 accum) -> LDS bf16 hi/lo.
// Phase 2: z @ W_a (+b, ReLU). Phase 3: u @ W_b (+b, ReLU) -> fp16 global;
// HEAD variant continues through W_h1 and the 64->2 head -> fp32 out.
// MFMA 16x16x32 layouts (verified R3): A[m=lane&15][k=quad*8+j],
// B = Wt[n=lane&15][k], C/D col=lane&15 row=quad*4+reg.
template <bool HEAD>
__global__ __launch_bounds__(256, 6)
void fused_layer_k(const _Float16* __restrict__ h_in,
                   const int* __restrict__ offs, const int* __restrict__ csr,
                   const float* __restrict__ eps, int layer,
                   const unsigned short* __restrict__ WAhi, const unsigned short* __restrict__ WAlo,
                   const float* __restrict__ ba,
                   const unsigned short* __restrict__ WBhi, const unsigned short* __restrict__ WBlo,
                   const float* __restrict__ bb,
                   const unsigned short* __restrict__ WHhi, const unsigned short* __restrict__ WHlo,
                   const float* __restrict__ bh1,
                   const float* __restrict__ W2, const float* __restrict__ b2,
                   void* __restrict__ outp) {
    __shared__ unsigned short Zhi[32 * 136];   // 8,704 B
    __shared__ unsigned short Zlo[32 * 136];
    const int t = threadIdx.x;
    const int wave = t >> 6, lane = t & 63;
    const int m = lane & 15, quad = lane >> 4;
    const int row0 = blockIdx.x * 32;
    const float sc = 1.0f + eps[layer];

    // ---------- phase 1: gather-aggregate (fp16 rows, 16 lanes/row) -> LDS
    {
        const int quart = lane >> 4;            // 0..3: 4 nodes per wave-pass
        const int l16 = lane & 15;              // 16 lanes x 8 feats = 128
        const hv8* __restrict__ h8 = (const hv8*)h_in;   // row stride = 16 hv8
        for (int g = 0; g < 2; ++g) {
            const int r = wave * 8 + g * 4 + quart;
            const int node = row0 + r;
            float a0[8] = {0,0,0,0,0,0,0,0};
            float a1[8] = {0,0,0,0,0,0,0,0};
            float o[8]  = {0,0,0,0,0,0,0,0};
            if (node < N_NODES) {
                const int beg = offs[node], end = offs[node + 1];
                int j = beg;
                for (; j + 4 <= end; j += 4) {
                    int s0 = csr[j], s1 = csr[j+1], s2 = csr[j+2], s3 = csr[j+3];
                    hv8 v0 = h8[(size_t)s0 * 16 + l16];
                    hv8 v1 = h8[(size_t)s1 * 16 + l16];
                    hv8 v2 = h8[(size_t)s2 * 16 + l16];
                    hv8 v3 = h8[(size_t)s3 * 16 + l16];
#pragma unroll
                    for (int e = 0; e < 8; ++e) {
                        a0[e] += (float)v0[e] + (float)v2[e];
                        a1[e] += (float)v1[e] + (float)v3[e];
                    }
                }
                for (; j < end; ++j) {
                    hv8 v = h8[(size_t)csr[j] * 16 + l16];
#pragma unroll
                    for (int e = 0; e < 8; ++e) a0[e] += (float)v[e];
                }
                hv8 self = h8[(size_t)node * 16 + l16];
#pragma unroll
                for (int e = 0; e < 8; ++e)
                    o[e] = sc * (float)self[e] + (a0[e] + a1[e]);
            }
            us4 hi0, hi1, lo0, lo1;
#pragma unroll
            for (int e = 0; e < 4; ++e) {
                hi0[e] = f2bf(o[e]);     lo0[e] = f2bf(o[e]     - bf2f(hi0[e]));
                hi1[e] = f2bf(o[e + 4]); lo1[e] = f2bf(o[e + 4] - bf2f(hi1[e]));
            }
            *(us4*)&Zhi[r * 136 + l16 * 8]     = hi0;
            *(us4*)&Zhi[r * 136 + l16 * 8 + 4] = hi1;
            *(us4*)&Zlo[r * 136 + l16 * 8]     = lo0;
            *(us4*)&Zlo[r * 136 + l16 * 8 + 4] = lo1;
        }
    }

    // ---------- W_a fragments (cols: wave*32 + ct*16 + m)
    short8 wh[2][4], wl[2][4];
    for (int ct = 0; ct < 2; ++ct) {
        int n = wave * 32 + ct * 16 + m;
        for (int ks = 0; ks < 4; ++ks) {
            wh[ct][ks] = *(const short8*)&WAhi[n * 128 + ks * 32 + quad * 8];
            wl[ct][ks] = *(const short8*)&WAlo[n * 128 + ks * 32 + quad * 8];
        }
    }
    __syncthreads();

    // ---------- phase 2: z @ W_a   (2 row-strips of 16)
    f32x4 acc[2][2];
    for (int s = 0; s < 2; ++s)
        for (int ct = 0; ct < 2; ++ct) acc[s][ct] = (f32x4){0, 0, 0, 0};
    for (int s = 0; s < 2; ++s) {
        const int r = s * 16 + m;
        for (int ks = 0; ks < 4; ++ks) {
            short8 zh = *(const short8*)&Zhi[r * 136 + ks * 32 + quad * 8];
            short8 zl = *(const short8*)&Zlo[r * 136 + ks * 32 + quad * 8];
            for (int ct = 0; ct < 2; ++ct) {
                acc[s][ct] = __builtin_amdgcn_mfma_f32_16x16x32_bf16(zh, wh[ct][ks], acc[s][ct], 0, 0, 0);
                acc[s][ct] = __builtin_amdgcn_mfma_f32_16x16x32_bf16(zh, wl[ct][ks], acc[s][ct], 0, 0, 0);
                acc[s][ct] = __builtin_amdgcn_mfma_f32_16x16x32_bf16(zl, wh[ct][ks], acc[s][ct], 0, 0, 0);
            }
        }
    }

    // ---------- W_b fragments
    for (int ct = 0; ct < 2; ++ct) {
        int n = wave * 32 + ct * 16 + m;
        for (int ks = 0; ks < 4; ++ks) {
            wh[ct][ks] = *(const short8*)&WBhi[n * 128 + ks * 32 + quad * 8];
            wl[ct][ks] = *(const short8*)&WBlo[n * 128 + ks * 32 + quad * 8];
        }
    }
    __syncthreads();   // all z reads done; safe to overwrite LDS

    // ---------- u = relu(acc + ba) -> LDS bf16 hi/lo
    for (int s = 0; s < 2; ++s) {
        for (int ct = 0; ct < 2; ++ct) {
            int c = wave * 32 + ct * 16 + m;
            float bac = ba[c];
            for (int i = 0; i < 4; ++i) {
                int r = s * 16 + quad * 4 + i;
                float v = fmaxf(acc[s][ct][i] + bac, 0.0f);
                unsigned short hv = f2bf(v);
                Zhi[r * 136 + c] = hv;
                Zlo[r * 136 + c] = f2bf(v - bf2f(hv));
            }
        }
    }
    __syncthreads();

    // ---------- phase 3: u @ W_b
    for (int s = 0; s < 2; ++s)
        for (int ct = 0; ct < 2; ++ct) acc[s][ct] = (f32x4){0, 0, 0, 0};
    for (int s = 0; s < 2; ++s) {
        const int r = s * 16 + m;
        for (int ks = 0; ks < 4; ++ks) {
            short8 zh = *(const short8*)&Zhi[r * 136 + ks * 32 + quad * 8];
            short8 zl = *(const short8*)&Zlo[r * 136 + ks * 32 + quad * 8];
            for (int ct = 0; ct < 2; ++ct) {
                acc[s][ct] = __builtin_amdgcn_mfma_f32_16x16x32_bf16(zh, wh[ct][ks], acc[s][ct], 0, 0, 0);
                acc[s][ct] = __builtin_amdgcn_mfma_f32_16x16x32_bf16(zh, wl[ct][ks], acc[s][ct], 0, 0, 0);
                acc[s][ct] = __builtin_amdgcn_mfma_f32_16x16x32_bf16(zl, wh[ct][ks], acc[s][ct], 0, 0, 0);
            }
        }
    }

    if (!HEAD) {
        // ---------- h = relu(acc + bb) -> fp16 global
        _Float16* hout = (_Float16*)outp;
        for (int s = 0; s < 2; ++s) {
            for (int ct = 0; ct < 2; ++ct) {
                int c = wave * 32 + ct * 16 + m;
                float bbc = bb[c];
                for (int i = 0; i < 4; ++i) {
                    int row = row0 + s * 16 + quad * 4 + i;
                    if (row < N_NODES)
                        hout[(size_t)row * 128 + c] = (_Float16)fmaxf(acc[s][ct][i] + bbc, 0.0f);
                }
            }
        }
    } else {
        // ---------- W_h1 fragments (64 cols: wave*16 + m)
        short8 hh[4], hl[4];
        {
            int n = wave * 16 + m;
            for (int ks = 0; ks < 4; ++ks) {
                hh[ks] = *(const short8*)&WHhi[n * 128 + ks * 32 + quad * 8];
                hl[ks] = *(const short8*)&WHlo[n * 128 + ks * 32 + quad * 8];
            }
        }
        __syncthreads();   // all u reads done

        // ---------- h = relu(acc + bb) -> LDS bf16 hi/lo
        for (int s = 0; s < 2; ++s) {
            for (int ct = 0; ct < 2; ++ct) {
                int c = wave * 32 + ct * 16 + m;
                float bbc = bb[c];
                for (int i = 0; i < 4; ++i) {
                    int r = s * 16 + quad * 4 + i;
                    float v = fmaxf(acc[s][ct][i] + bbc, 0.0f);
                    unsigned short hv = f2bf(v);
                    Zhi[r * 136 + c] = hv;
                    Zlo[r * 136 + c] = f2bf(v - bf2f(hv));
                }
            }
        }
        __syncthreads();

        // ---------- phase 4: h @ W_h1 (128 -> 64)
        f32x4 a3[2];
        for (int s = 0; s < 2; ++s) a3[s] = (f32x4){0, 0, 0, 0};
        for (int s = 0; s < 2; ++s) {
            const int r = s * 16 + m;
            for (int ks = 0; ks < 4; ++ks) {
                short8 zh = *(const short8*)&Zhi[r * 136 + ks * 32 + quad * 8];
                short8 zl = *(const short8*)&Zlo[r * 136 + ks * 32 + quad * 8];
                a3[s] = __builtin_amdgcn_mfma_f32_16x16x32_bf16(zh, hh[ks], a3[s], 0, 0, 0);
                a3[s] = __builtin_amdgcn_mfma_f32_16x16x32_bf16(zh, hl[ks], a3[s], 0, 0, 0);
                a3[s] = __builtin_amdgcn_mfma_f32_16x16x32_bf16(zl, hh[ks], a3[s], 0, 0, 0);
            }
        }
        __syncthreads();   // phase-4 reads done; reuse LDS as fp32

        float* Hid = (float*)Zhi;   // 32 x 68 fp32 = 8,704 B (fits in Zhi)
        for (int s = 0; s < 2; ++s) {
            int c = wave * 16 + m;
            float bc = bh1[c];
            for (int i = 0; i < 4; ++i) {
                int r = s * 16 + quad * 4 + i;
                Hid[r * 68 + c] = fmaxf(a3[s][i] + bc, 0.0f);
            }
        }
        __syncthreads();

        // ---------- phase 5: hid @ W_h2 (64 -> 2) + b2 -> out
        if (t < 64) {
            float* outF = (float*)outp;
            int r = t >> 1, col = t & 1;
            float a = b2[col];
#pragma unroll
            for (int j = 0; j < 64; ++j) a += Hid[r * 68 + j] * W2[j * 2 + col];
            int node = row0 + r;
            if (node < N_NODES) outF[(size_t)node * 2 + col] = a;
        }
    }
}

// ------------------------------------------------------------------ launch

extern "C" void kernel_launch(void* const* d_in, const int* in_sizes, int n_in,
                              void* d_out, int out_size, void* d_ws, size_t ws_size,
                              hipStream_t stream) {
    const float* x    = (const float*)d_in[0];
    const int*   ei   = (const int*)d_in[1];
    const float* eps  = (const float*)d_in[2];
    const float* W_a  = (const float*)d_in[3];
    const float* b_a  = (const float*)d_in[4];
    const float* W_b  = (const float*)d_in[5];
    const float* b_b  = (const float*)d_in[6];
    const float* W_h1 = (const float*)d_in[7];
    const float* b_h1 = (const float*)d_in[8];
    const float* W_h2 = (const float*)d_in[9];
    const float* b_h2 = (const float*)d_in[10];
    float* out = (float*)d_out;

    const int N = N_NODES, E = N_EDGES;
    const int* src = ei;
    const int* dst = ei + E;

    char* ws = (char*)d_ws;
    size_t off = 0;
    auto carve = [&](size_t bytes) {
        char* p = ws + off;
        off = (off + bytes + 255) & ~(size_t)255;
        return p;
    };
    _Float16* xh   = (_Float16*)carve((size_t)N * HID * sizeof(_Float16));
    _Float16* bufA = (_Float16*)carve((size_t)N * HID * sizeof(_Float16));
    _Float16* bufB = (_Float16*)carve((size_t)N * HID * sizeof(_Float16));
    int*   cnt    = (int*)carve((size_t)N * sizeof(int));
    int*   offs   = (int*)carve((size_t)(N + 1) * sizeof(int));
    int*   rank   = (int*)carve((size_t)E * sizeof(int));
    int*   csr    = (int*)carve((size_t)E * sizeof(int));
    int*   bsum   = (int*)carve(64 * sizeof(int));
    unsigned short* whi = (unsigned short*)carve(7 * 16384 * sizeof(unsigned short));
    unsigned short* wlo = (unsigned short*)carve(7 * 16384 * sizeof(unsigned short));
    (void)ws_size;

    // ---- CSR build (rank trick: no atomics in fill)
    hipMemsetAsync(cnt, 0, (size_t)N * sizeof(int), stream);
    count_k<<<(E + 255) / 256, 256, 0, stream>>>(dst, cnt, rank, E);
    const int SB = (N + SCAN_CHUNK - 1) / SCAN_CHUNK;
    scan1_k<<<SB, 256, 0, stream>>>(cnt, bsum, N);
    scan2_k<<<1, 64, 0, stream>>>(bsum, offs, SB, N);
    scan3_k<<<SB, 256, 0, stream>>>(cnt, bsum, offs, N);
    fill2_k<<<(E + 255) / 256, 256, 0, stream>>>(src, dst, rank, offs, csr, E);

    // ---- input + weight conversion
    xcvt_k<<<(N * HID / 4 + 255) / 256, 256, 0, stream>>>(x, xh, N * HID / 4);
    wcvt_k<<<(106496 + 255) / 256, 256, 0, stream>>>(W_a, W_b, W_h1, whi, wlo);

    const int grid = (N + 31) / 32;
    #define WSLOT(s) (whi + (s) * 16384), (wlo + (s) * 16384)

    fused_layer_k<false><<<grid, 256, 0, stream>>>(
        xh, offs, csr, eps, 0,
        WSLOT(0), b_a + 0 * 128, WSLOT(1), b_b + 0 * 128,
        (const unsigned short*)nullptr, (const unsigned short*)nullptr,
        (const float*)nullptr, (const float*)nullptr, (const float*)nullptr, (void*)bufA);
    fused_layer_k<false><<<grid, 256, 0, stream>>>(
        bufA, offs, csr, eps, 1,
        WSLOT(2), b_a + 1 * 128, WSLOT(3), b_b + 1 * 128,
        (const unsigned short*)nullptr, (const unsigned short*)nullptr,
        (const float*)nullptr, (const float*)nullptr, (const float*)nullptr, (void*)bufB);
    fused_layer_k<true><<<grid, 256, 0, stream>>>(
        bufB, offs, csr, eps, 2,
        WSLOT(4), b_a + 2 * 128, WSLOT(5), b_b + 2 * 128,
        WSLOT(6), b_h1, W_h2, b_h2, (void*)out);
}

// Round 8
// 354.322 us; speedup vs baseline: 1.2757x; 1.0566x over previous
//
#include <hip/hip_runtime.h>
#include <hip/hip_bf16.h>

#define N_NODES 50000
#define N_EDGES 800000
#define HID 128

#define NB 391      // dst buckets: dst>>7, 128 nodes each
#define NBLK 160    // histogram/scatter blocks
#define EPB 5000    // edges per block (NBLK*EPB == N_EDGES)

typedef __attribute__((ext_vector_type(8))) short short8;     // 8 bf16 (4 VGPR)
typedef __attribute__((ext_vector_type(4))) float f32x4;      // MFMA acc
typedef __attribute__((ext_vector_type(4))) unsigned short us4;
typedef _Float16 hv8 __attribute__((ext_vector_type(8)));     // 8 fp16 (16 B)
typedef _Float16 hv4 __attribute__((ext_vector_type(4)));     // 4 fp16 (8 B)

__device__ __forceinline__ unsigned short f2bf(float v) {
    union { float f; unsigned u; } x; x.f = v;
    unsigned r = x.u + 0x7fff + ((x.u >> 16) & 1);   // RTN-even
    return (unsigned short)(r >> 16);
}
__device__ __forceinline__ float bf2f(unsigned short b) {
    union { unsigned u; float f; } x; x.u = ((unsigned)b) << 16;
    return x.f;
}

// ----------------------------- CSR build: streaming 2-level counting sort

// Phase H: per-block LDS histogram over NB buckets -> bh[b*NBLK + blk]
__global__ __launch_bounds__(256)
void hist_k(const int* __restrict__ dst, int* __restrict__ bh, int E) {
    __shared__ int h[NB];
    for (int i = threadIdx.x; i < NB; i += 256) h[i] = 0;
    __syncthreads();
    const int base = blockIdx.x * EPB;
    const int end = min(base + EPB, E);
    for (int i = base + threadIdx.x; i < end; i += 256)
        atomicAdd(&h[dst[i] >> 7], 1);
    __syncthreads();
    for (int i = threadIdx.x; i < NB; i += 256)
        bh[i * NBLK + blockIdx.x] = h[i];
}

// Phase S: 3-pass exclusive scan over n = NB*NBLK ints (8 per thread)
__global__ __launch_bounds__(256)
void scanA_k(const int* __restrict__ in, int* __restrict__ bsum, int n) {
    const int t = threadIdx.x, base = blockIdx.x * 2048 + t * 8;
    int s = 0;
#pragma unroll
    for (int k = 0; k < 8; ++k) s += (base + k < n) ? in[base + k] : 0;
    __shared__ int sh[256];
    sh[t] = s;
    __syncthreads();
    for (int o = 128; o > 0; o >>= 1) {
        if (t < o) sh[t] += sh[t + o];
        __syncthreads();
    }
    if (t == 0) bsum[blockIdx.x] = sh[0];
}

__global__ __launch_bounds__(64)
void scanB_k(int* __restrict__ bsum, int B) {
    const int t = threadIdx.x;
    int own = (t < B) ? bsum[t] : 0;
    int v = own;
    for (int o = 1; o < 64; o <<= 1) {
        int u = __shfl_up(v, o, 64);
        if (t >= o) v += u;
    }
    if (t < B) bsum[t] = v - own;
}

__global__ __launch_bounds__(256)
void scanC_k(const int* __restrict__ in, const int* __restrict__ bsum,
             int* __restrict__ out, int n) {
    const int t = threadIdx.x, base = blockIdx.x * 2048 + t * 8;
    int v[8]; int s = 0;
#pragma unroll
    for (int k = 0; k < 8; ++k) { v[k] = (base + k < n) ? in[base + k] : 0; s += v[k]; }
    __shared__ int sh[256];
    sh[t] = s;
    __syncthreads();
    for (int o = 1; o < 256; o <<= 1) {
        int u = (t >= o) ? sh[t - o] : 0;
        __syncthreads();
        sh[t] += u;
        __syncthreads();
    }
    int run = ((t == 0) ? 0 : sh[t - 1]) + bsum[blockIdx.x];
#pragma unroll
    for (int k = 0; k < 8; ++k) {
        if (base + k < n) out[base + k] = run;
        run += v[k];
    }
}

// Phase C: scatter edges to bucket-segmented tmp via LDS cursors
__global__ __launch_bounds__(256)
void scatter_k(const int* __restrict__ src, const int* __restrict__ dst,
               const int* __restrict__ bhs, int2* __restrict__ tmp, int E) {
    __shared__ int cur[NB];
    for (int i = threadIdx.x; i < NB; i += 256) cur[i] = bhs[i * NBLK + blockIdx.x];
    __syncthreads();
    const int base = blockIdx.x * EPB;
    const int end = min(base + EPB, E);
    for (int i = base + threadIdx.x; i < end; i += 256) {
        int d = dst[i];
        int p = atomicAdd(&cur[d >> 7], 1);
        tmp[p] = make_int2(src[i], d);
    }
}

// Phase D: one block per bucket — local 128-counter sort; writes offs + csr
__global__ __launch_bounds__(256)
void bucket_k(const int2* __restrict__ tmp, const int* __restrict__ bhs,
              int* __restrict__ offs, int* __restrict__ csr, int E, int N) {
    const int b = blockIdx.x;
    const int t = threadIdx.x;
    __shared__ int hist[128], excl[128], cur[128];
    const int bstart = bhs[b * NBLK];
    const int bend = (b + 1 < NB) ? bhs[(b + 1) * NBLK] : E;
    if (t < 128) hist[t] = 0;
    __syncthreads();
    for (int i = bstart + t; i < bend; i += 256)
        atomicAdd(&hist[tmp[i].y & 127], 1);
    __syncthreads();
    if (t < 128) excl[t] = hist[t];
    __syncthreads();
    for (int o = 1; o < 128; o <<= 1) {        // Hillis inclusive scan
        int u = (t < 128 && t >= o) ? excl[t - o] : 0;
        __syncthreads();
        if (t < 128) excl[t] += u;
        __syncthreads();
    }
    const int node0 = b * 128;
    if (t < 128) {
        int base = bstart + ((t == 0) ? 0 : excl[t - 1]);
        if (node0 + t < N) offs[node0 + t] = base;
        cur[t] = base;
    }
    if (b == 0 && t == 0) offs[N] = E;
    __syncthreads();
    for (int i = bstart + t; i < bend; i += 256) {
        int2 e = tmp[i];
        int p = atomicAdd(&cur[e.y & 127], 1);
        csr[p] = e.x;
    }
}

// --------------------------------------------------- x -> fp16 table
__global__ __launch_bounds__(256)
void xcvt_k(const float* __restrict__ x, _Float16* __restrict__ xh, int n4) {
    int i = blockIdx.x * 256 + threadIdx.x;
    if (i < n4) {
        float4 v = *(const float4*)&x[i * 4];
        hv4 o;
        o.x = (_Float16)v.x; o.y = (_Float16)v.y;
        o.z = (_Float16)v.z; o.w = (_Float16)v.w;
        *(hv4*)&xh[i * 4] = o;
    }
}

// ------------------------------------------- weight pre-split (bf16 hi/lo)
// Transposed bf16 hi/lo: Wt[n][k], slot stride 16384 elems.
// Slots: 2l = W_a[l], 2l+1 = W_b[l] (l=0..2), 6 = W_h1.
__global__ __launch_bounds__(256)
void wcvt_k(const float* __restrict__ Wa, const float* __restrict__ Wb,
            const float* __restrict__ Wh1,
            unsigned short* __restrict__ whi, unsigned short* __restrict__ wlo) {
    int id = blockIdx.x * 256 + threadIdx.x;
    float v; int dst;
    if (id < 49152) {                      // 3 x 128x128 W_a
        int l = id >> 14, e = id & 16383;
        v = Wa[id];
        int n = e & 127, k = e >> 7;
        dst = (2 * l) * 16384 + n * 128 + k;
    } else if (id < 98304) {               // 3 x 128x128 W_b
        int id2 = id - 49152;
        int l = id2 >> 14, e = id2 & 16383;
        v = Wb[id2];
        int n = e & 127, k = e >> 7;
        dst = (2 * l + 1) * 16384 + n * 128 + k;
    } else if (id < 106496) {              // 128x64 W_h1
        int e = id - 98304;
        v = Wh1[e];
        int n = e & 63, k = e >> 6;
        dst = 6 * 16384 + n * 128 + k;
    } else return;
    unsigned short hi = f2bf(v);
    whi[dst] = hi;
    wlo[dst] = f2bf(v - bf2f(hi));
}

// ------------------------------------------------------- fused GIN layer
// One block = 32 nodes. Gather: 16 lanes x 16 B (hv8) per fp16 row -> one
// wave-load fetches 4 rows. Phase 1: CSR gather (fp32 accum) -> LDS bf16
// hi/lo. Phase 2: z @ W_a (+b, ReLU). Phase 3: u @ W_b (+b, ReLU) -> fp16
// global; HEAD continues through W_h1 and the 64->2 head -> fp32 out.
// MFMA 16x16x32 layouts (verified R3): A[m=lane&15][k=quad*8+j],
// B = Wt[n=lane&15][k], C/D col=lane&15 row=quad*4+reg.
template <bool HEAD>
__global__ __launch_bounds__(256, 6)
void fused_layer_k(const _Float16* __restrict__ h_in,
                   const int* __restrict__ offs, const int* __restrict__ csr,
                   const float* __restrict__ eps, int layer,
                   const unsigned short* __restrict__ WAhi, const unsigned short* __restrict__ WAlo,
                   const float* __restrict__ ba,
                   const unsigned short* __restrict__ WBhi, const unsigned short* __restrict__ WBlo,
                   const float* __restrict__ bb,
                   const unsigned short* __restrict__ WHhi, const unsigned short* __restrict__ WHlo,
                   const float* __restrict__ bh1,
                   const float* __restrict__ W2, const float* __restrict__ b2,
                   void* __restrict__ outp) {
    __shared__ unsigned short Zhi[32 * 136];   // 8,704 B
    __shared__ unsigned short Zlo[32 * 136];
    const int t = threadIdx.x;
    const int wave = t >> 6, lane = t & 63;
    const int m = lane & 15, quad = lane >> 4;
    const int row0 = blockIdx.x * 32;
    const float sc = 1.0f + eps[layer];

    // ---------- phase 1: gather-aggregate (fp16 rows, 16 lanes/row) -> LDS
    {
        const int quart = lane >> 4;            // 0..3: 4 nodes per wave-pass
        const int l16 = lane & 15;              // 16 lanes x 8 feats = 128
        const hv8* __restrict__ h8 = (const hv8*)h_in;   // row stride = 16 hv8
        for (int g = 0; g < 2; ++g) {
            const int r = wave * 8 + g * 4 + quart;
            const int node = row0 + r;
            float a0[8] = {0,0,0,0,0,0,0,0};
            float a1[8] = {0,0,0,0,0,0,0,0};
            float o[8]  = {0,0,0,0,0,0,0,0};
            if (node < N_NODES) {
                const int beg = offs[node], end = offs[node + 1];
                int j = beg;
                for (; j + 4 <= end; j += 4) {
                    int s0 = csr[j], s1 = csr[j+1], s2 = csr[j+2], s3 = csr[j+3];
                    hv8 v0 = h8[(size_t)s0 * 16 + l16];
                    hv8 v1 = h8[(size_t)s1 * 16 + l16];
                    hv8 v2 = h8[(size_t)s2 * 16 + l16];
                    hv8 v3 = h8[(size_t)s3 * 16 + l16];
#pragma unroll
                    for (int e = 0; e < 8; ++e) {
                        a0[e] += (float)v0[e] + (float)v2[e];
                        a1[e] += (float)v1[e] + (float)v3[e];
                    }
                }
                for (; j < end; ++j) {
                    hv8 v = h8[(size_t)csr[j] * 16 + l16];
#pragma unroll
                    for (int e = 0; e < 8; ++e) a0[e] += (float)v[e];
                }
                hv8 self = h8[(size_t)node * 16 + l16];
#pragma unroll
                for (int e = 0; e < 8; ++e)
                    o[e] = sc * (float)self[e] + (a0[e] + a1[e]);
            }
            us4 hi0, hi1, lo0, lo1;
#pragma unroll
            for (int e = 0; e < 4; ++e) {
                hi0[e] = f2bf(o[e]);     lo0[e] = f2bf(o[e]     - bf2f(hi0[e]));
                hi1[e] = f2bf(o[e + 4]); lo1[e] = f2bf(o[e + 4] - bf2f(hi1[e]));
            }
            *(us4*)&Zhi[r * 136 + l16 * 8]     = hi0;
            *(us4*)&Zhi[r * 136 + l16 * 8 + 4] = hi1;
            *(us4*)&Zlo[r * 136 + l16 * 8]     = lo0;
            *(us4*)&Zlo[r * 136 + l16 * 8 + 4] = lo1;
        }
    }

    // ---------- W_a fragments (cols: wave*32 + ct*16 + m)
    short8 wh[2][4], wl[2][4];
    for (int ct = 0; ct < 2; ++ct) {
        int n = wave * 32 + ct * 16 + m;
        for (int ks = 0; ks < 4; ++ks) {
            wh[ct][ks] = *(const short8*)&WAhi[n * 128 + ks * 32 + quad * 8];
            wl[ct][ks] = *(const short8*)&WAlo[n * 128 + ks * 32 + quad * 8];
        }
    }
    __syncthreads();

    // ---------- phase 2: z @ W_a   (2 row-strips of 16)
    f32x4 acc[2][2];
    for (int s = 0; s < 2; ++s)
        for (int ct = 0; ct < 2; ++ct) acc[s][ct] = (f32x4){0, 0, 0, 0};
    for (int s = 0; s < 2; ++s) {
        const int r = s * 16 + m;
        for (int ks = 0; ks < 4; ++ks) {
            short8 zh = *(const short8*)&Zhi[r * 136 + ks * 32 + quad * 8];
            short8 zl = *(const short8*)&Zlo[r * 136 + ks * 32 + quad * 8];
            for (int ct = 0; ct < 2; ++ct) {
                acc[s][ct] = __builtin_amdgcn_mfma_f32_16x16x32_bf16(zh, wh[ct][ks], acc[s][ct], 0, 0, 0);
                acc[s][ct] = __builtin_amdgcn_mfma_f32_16x16x32_bf16(zh, wl[ct][ks], acc[s][ct], 0, 0, 0);
                acc[s][ct] = __builtin_amdgcn_mfma_f32_16x16x32_bf16(zl, wh[ct][ks], acc[s][ct], 0, 0, 0);
            }
        }
    }

    // ---------- W_b fragments
    for (int ct = 0; ct < 2; ++ct) {
        int n = wave * 32 + ct * 16 + m;
        for (int ks = 0; ks < 4; ++ks) {
            wh[ct][ks] = *(const short8*)&WBhi[n * 128 + ks * 32 + quad * 8];
            wl[ct][ks] = *(const short8*)&WBlo[n * 128 + ks * 32 + quad * 8];
        }
    }
    __syncthreads();   // all z reads done; safe to overwrite LDS

    // ---------- u = relu(acc + ba) -> LDS bf16 hi/lo
    for (int s = 0; s < 2; ++s) {
        for (int ct = 0; ct < 2; ++ct) {
            int c = wave * 32 + ct * 16 + m;
            float bac = ba[c];
            for (int i = 0; i < 4; ++i) {
                int r = s * 16 + quad * 4 + i;
                float v = fmaxf(acc[s][ct][i] + bac, 0.0f);
                unsigned short hv = f2bf(v);
                Zhi[r * 136 + c] = hv;
                Zlo[r * 136 + c] = f2bf(v - bf2f(hv));
            }
        }
    }
    __syncthreads();

    // ---------- phase 3: u @ W_b
    for (int s = 0; s < 2; ++s)
        for (int ct = 0; ct < 2; ++ct) acc[s][ct] = (f32x4){0, 0, 0, 0};
    for (int s = 0; s < 2; ++s) {
        const int r = s * 16 + m;
        for (int ks = 0; ks < 4; ++ks) {
            short8 zh = *(const short8*)&Zhi[r * 136 + ks * 32 + quad * 8];
            short8 zl = *(const short8*)&Zlo[r * 136 + ks * 32 + quad * 8];
            for (int ct = 0; ct < 2; ++ct) {
                acc[s][ct] = __builtin_amdgcn_mfma_f32_16x16x32_bf16(zh, wh[ct][ks], acc[s][ct], 0, 0, 0);
                acc[s][ct] = __builtin_amdgcn_mfma_f32_16x16x32_bf16(zh, wl[ct][ks], acc[s][ct], 0, 0, 0);
                acc[s][ct] = __builtin_amdgcn_mfma_f32_16x16x32_bf16(zl, wh[ct][ks], acc[s][ct], 0, 0, 0);
            }
        }
    }

    if (!HEAD) {
        // ---------- h = relu(acc + bb) -> fp16 global
        _Float16* hout = (_Float16*)outp;
        for (int s = 0; s < 2; ++s) {
            for (int ct = 0; ct < 2; ++ct) {
                int c = wave * 32 + ct * 16 + m;
                float bbc = bb[c];
                for (int i = 0; i < 4; ++i) {
                    int row = row0 + s * 16 + quad * 4 + i;
                    if (row < N_NODES)
                        hout[(size_t)row * 128 + c] = (_Float16)fmaxf(acc[s][ct][i] + bbc, 0.0f);
                }
            }
        }
    } else {
        // ---------- W_h1 fragments (64 cols: wave*16 + m)
        short8 hh[4], hl[4];
        {
            int n = wave * 16 + m;
            for (int ks = 0; ks < 4; ++ks) {
                hh[ks] = *(const short8*)&WHhi[n * 128 + ks * 32 + quad * 8];
                hl[ks] = *(const short8*)&WHlo[n * 128 + ks * 32 + quad * 8];
            }
        }
        __syncthreads();   // all u reads done

        // ---------- h = relu(acc + bb) -> LDS bf16 hi/lo
        for (int s = 0; s < 2; ++s) {
            for (int ct = 0; ct < 2; ++ct) {
                int c = wave * 32 + ct * 16 + m;
                float bbc = bb[c];
                for (int i = 0; i < 4; ++i) {
                    int r = s * 16 + quad * 4 + i;
                    float v = fmaxf(acc[s][ct][i] + bbc, 0.0f);
                    unsigned short hv = f2bf(v);
                    Zhi[r * 136 + c] = hv;
                    Zlo[r * 136 + c] = f2bf(v - bf2f(hv));
                }
            }
        }
        __syncthreads();

        // ---------- phase 4: h @ W_h1 (128 -> 64)
        f32x4 a3[2];
        for (int s = 0; s < 2; ++s) a3[s] = (f32x4){0, 0, 0, 0};
        for (int s = 0; s < 2; ++s) {
            const int r = s * 16 + m;
            for (int ks = 0; ks < 4; ++ks) {
                short8 zh = *(const short8*)&Zhi[r * 136 + ks * 32 + quad * 8];
                short8 zl = *(const short8*)&Zlo[r * 136 + ks * 32 + quad * 8];
                a3[s] = __builtin_amdgcn_mfma_f32_16x16x32_bf16(zh, hh[ks], a3[s], 0, 0, 0);
                a3[s] = __builtin_amdgcn_mfma_f32_16x16x32_bf16(zh, hl[ks], a3[s], 0, 0, 0);
                a3[s] = __builtin_amdgcn_mfma_f32_16x16x32_bf16(zl, hh[ks], a3[s], 0, 0, 0);
            }
        }
        __syncthreads();   // phase-4 reads done; reuse LDS as fp32

        float* Hid = (float*)Zhi;   // 32 x 68 fp32 = 8,704 B (fits in Zhi)
        for (int s = 0; s < 2; ++s) {
            int c = wave * 16 + m;
            float bc = bh1[c];
            for (int i = 0; i < 4; ++i) {
                int r = s * 16 + quad * 4 + i;
                Hid[r * 68 + c] = fmaxf(a3[s][i] + bc, 0.0f);
            }
        }
        __syncthreads();

        // ---------- phase 5: hid @ W_h2 (64 -> 2) + b2 -> out
        if (t < 64) {
            float* outF = (float*)outp;
            int r = t >> 1, col = t & 1;
            float a = b2[col];
#pragma unroll
            for (int j = 0; j < 64; ++j) a += Hid[r * 68 + j] * W2[j * 2 + col];
            int node = row0 + r;
            if (node < N_NODES) outF[(size_t)node * 2 + col] = a;
        }
    }
}

// ------------------------------------------------------------------ launch

extern "C" void kernel_launch(void* const* d_in, const int* in_sizes, int n_in,
                              void* d_out, int out_size, void* d_ws, size_t ws_size,
                              hipStream_t stream) {
    const float* x    = (const float*)d_in[0];
    const int*   ei   = (const int*)d_in[1];
    const float* eps  = (const float*)d_in[2];
    const float* W_a  = (const float*)d_in[3];
    const float* b_a  = (const float*)d_in[4];
    const float* W_b  = (const float*)d_in[5];
    const float* b_b  = (const float*)d_in[6];
    const float* W_h1 = (const float*)d_in[7];
    const float* b_h1 = (const float*)d_in[8];
    const float* W_h2 = (const float*)d_in[9];
    const float* b_h2 = (const float*)d_in[10];
    float* out = (float*)d_out;

    const int N = N_NODES, E = N_EDGES;
    const int* src = ei;
    const int* dst = ei + E;

    char* ws = (char*)d_ws;
    size_t off = 0;
    auto carve = [&](size_t bytes) {
        char* p = ws + off;
        off = (off + bytes + 255) & ~(size_t)255;
        return p;
    };
    _Float16* xh   = (_Float16*)carve((size_t)N * HID * sizeof(_Float16));
    _Float16* bufA = (_Float16*)carve((size_t)N * HID * sizeof(_Float16));
    _Float16* bufB = (_Float16*)carve((size_t)N * HID * sizeof(_Float16));
    int2*  tmp    = (int2*)carve((size_t)E * sizeof(int2));
    int*   csr    = (int*)carve((size_t)E * sizeof(int));
    int*   offs   = (int*)carve((size_t)(N + 1) * sizeof(int));
    int*   bh     = (int*)carve((size_t)NB * NBLK * sizeof(int));
    int*   bhs    = (int*)carve((size_t)NB * NBLK * sizeof(int));
    int*   bsum   = (int*)carve(64 * sizeof(int));
    unsigned short* whi = (unsigned short*)carve(7 * 16384 * sizeof(unsigned short));
    unsigned short* wlo = (unsigned short*)carve(7 * 16384 * sizeof(unsigned short));
    (void)ws_size;

    // ---- CSR build: streaming counting sort (LDS atomics only)
    const int M = NB * NBLK;                     // 62,560
    const int SB = (M + 2047) / 2048;            // 31 scan blocks
    hist_k<<<NBLK, 256, 0, stream>>>(dst, bh, E);
    scanA_k<<<SB, 256, 0, stream>>>(bh, bsum, M);
    scanB_k<<<1, 64, 0, stream>>>(bsum, SB);
    scanC_k<<<SB, 256, 0, stream>>>(bh, bsum, bhs, M);
    scatter_k<<<NBLK, 256, 0, stream>>>(src, dst, bhs, tmp, E);
    bucket_k<<<NB, 256, 0, stream>>>(tmp, bhs, offs, csr, E, N);

    // ---- input + weight conversion
    xcvt_k<<<(N * HID / 4 + 255) / 256, 256, 0, stream>>>(x, xh, N * HID / 4);
    wcvt_k<<<(106496 + 255) / 256, 256, 0, stream>>>(W_a, W_b, W_h1, whi, wlo);

    const int grid = (N + 31) / 32;
    #define WSLOT(s) (whi + (s) * 16384), (wlo + (s) * 16384)

    fused_layer_k<false><<<grid, 256, 0, stream>>>(
        xh, offs, csr, eps, 0,
        WSLOT(0), b_a + 0 * 128, WSLOT(1), b_b + 0 * 128,
        (const unsigned short*)nullptr, (const unsigned short*)nullptr,
        (const float*)nullptr, (const float*)nullptr, (const float*)nullptr, (void*)bufA);
    fused_layer_k<false><<<grid, 256, 0, stream>>>(
        bufA, offs, csr, eps, 1,
        WSLOT(2), b_a + 1 * 128, WSLOT(3), b_b + 1 * 128,
        (const unsigned short*)nullptr, (const unsigned short*)nullptr,
        (const float*)nullptr, (const float*)nullptr, (const float*)nullptr, (void*)bufB);
    fused_layer_k<true><<<grid, 256, 0, stream>>>(
        bufB, offs, csr, eps, 2,
        WSLOT(4), b_a + 2 * 128, WSLOT(5), b_b + 2 * 128,
        WSLOT(6), b_h1, W_h2, b_h2, (void*)out);
}

// Round 10
// 328.382 us; speedup vs baseline: 1.3764x; 1.0790x over previous
//
#include <hip/hip_runtime.h>
#include <hip/hip_bf16.h>

#define N_NODES 50000
#define N_EDGES 800000
#define HID 128

#define NB 391      // dst buckets: dst>>7, 128 nodes each
#define NBLK 160    // histogram/scatter blocks
#define EPB 5000    // edges per block (NBLK*EPB == N_EDGES)

typedef __attribute__((ext_vector_type(8))) short short8;     // 8 bf16 (4 VGPR)
typedef __attribute__((ext_vector_type(4))) float f32x4;      // MFMA acc
typedef __attribute__((ext_vector_type(4))) unsigned short us4;
typedef _Float16 hv8 __attribute__((ext_vector_type(8)));     // 8 fp16 (16 B)
typedef _Float16 hv4 __attribute__((ext_vector_type(4)));     // 4 fp16 (8 B)

__device__ __forceinline__ unsigned short f2bf(float v) {
    union { float f; unsigned u; } x; x.f = v;
    unsigned r = x.u + 0x7fff + ((x.u >> 16) & 1);   // RTN-even
    return (unsigned short)(r >> 16);
}
__device__ __forceinline__ float bf2f(unsigned short b) {
    union { unsigned u; float f; } x; x.u = ((unsigned)b) << 16;
    return x.f;
}

// ----------------------------- CSR build: streaming 2-level counting sort

__global__ __launch_bounds__(256)
void hist_k(const int* __restrict__ dst, int* __restrict__ bh, int E) {
    __shared__ int h[NB];
    for (int i = threadIdx.x; i < NB; i += 256) h[i] = 0;
    __syncthreads();
    const int base = blockIdx.x * EPB;
    const int end = min(base + EPB, E);
    for (int i = base + threadIdx.x; i < end; i += 256)
        atomicAdd(&h[dst[i] >> 7], 1);
    __syncthreads();
    for (int i = threadIdx.x; i < NB; i += 256)
        bh[i * NBLK + blockIdx.x] = h[i];
}

// scanA: per-block sums of 2048-int chunks -> bsum[31]
__global__ __launch_bounds__(256)
void scanA_k(const int* __restrict__ in, int* __restrict__ bsum, int n) {
    const int t = threadIdx.x, base = blockIdx.x * 2048 + t * 8;
    int s = 0;
#pragma unroll
    for (int k = 0; k < 8; ++k) s += (base + k < n) ? in[base + k] : 0;
    __shared__ int sh[256];
    sh[t] = s;
    __syncthreads();
    for (int o = 128; o > 0; o >>= 1) {
        if (t < o) sh[t] += sh[t + o];
        __syncthreads();
    }
    if (t == 0) bsum[blockIdx.x] = sh[0];
}

// scanC: each block self-scans the (<=64) partials, then local scan + write
__global__ __launch_bounds__(256)
void scanC_k(const int* __restrict__ in, const int* __restrict__ bsum,
             int* __restrict__ out, int n, int B) {
    const int t = threadIdx.x, base = blockIdx.x * 2048 + t * 8;
    __shared__ int blockoff;
    if (t == 0) {
        int p = 0;
        for (int i = 0; i < blockIdx.x; ++i) p += bsum[i];   // B<=64, trivial
        blockoff = p;
    }
    int v[8]; int s = 0;
#pragma unroll
    for (int k = 0; k < 8; ++k) { v[k] = (base + k < n) ? in[base + k] : 0; s += v[k]; }
    __shared__ int sh[256];
    sh[t] = s;
    __syncthreads();
    for (int o = 1; o < 256; o <<= 1) {
        int u = (t >= o) ? sh[t - o] : 0;
        __syncthreads();
        sh[t] += u;
        __syncthreads();
    }
    int run = ((t == 0) ? 0 : sh[t - 1]) + blockoff;
#pragma unroll
    for (int k = 0; k < 8; ++k) {
        if (base + k < n) out[base + k] = run;
        run += v[k];
    }
}

// scatter: edges -> bucket-segmented tmp (packed: src<<7 | dst&127)
__global__ __launch_bounds__(256)
void scatter_k(const int* __restrict__ src, const int* __restrict__ dst,
               const int* __restrict__ bhs, int* __restrict__ tmp, int E) {
    __shared__ int cur[NB];
    for (int i = threadIdx.x; i < NB; i += 256) cur[i] = bhs[i * NBLK + blockIdx.x];
    __syncthreads();
    const int base = blockIdx.x * EPB;
    const int end = min(base + EPB, E);
    for (int i = base + threadIdx.x; i < end; i += 256) {
        int d = dst[i];
        int p = atomicAdd(&cur[d >> 7], 1);
        tmp[p] = (src[i] << 7) | (d & 127);
    }
}

// bucket: one block per bucket — 128-counter local sort; writes offs + csr
__global__ __launch_bounds__(256)
void bucket_k(const int* __restrict__ tmp, const int* __restrict__ bhs,
              int* __restrict__ offs, int* __restrict__ csr, int E, int N) {
    const int b = blockIdx.x;
    const int t = threadIdx.x;
    __shared__ int hist[128], excl[128], cur[128];
    const int bstart = bhs[b * NBLK];
    const int bend = (b + 1 < NB) ? bhs[(b + 1) * NBLK] : E;
    if (t < 128) hist[t] = 0;
    __syncthreads();
    for (int i = bstart + t; i < bend; i += 256)
        atomicAdd(&hist[tmp[i] & 127], 1);
    __syncthreads();
    if (t < 128) excl[t] = hist[t];
    __syncthreads();
    for (int o = 1; o < 128; o <<= 1) {
        int u = (t < 128 && t >= o) ? excl[t - o] : 0;
        __syncthreads();
        if (t < 128) excl[t] += u;
        __syncthreads();
    }
    const int node0 = b * 128;
    if (t < 128) {
        int base = bstart + ((t == 0) ? 0 : excl[t - 1]);
        if (node0 + t < N) offs[node0 + t] = base;
        cur[t] = base;
    }
    if (b == 0 && t == 0) offs[N] = E;
    __syncthreads();
    for (int i = bstart + t; i < bend; i += 256) {
        int e = tmp[i];
        int p = atomicAdd(&cur[e & 127], 1);
        csr[p] = e >> 7;
    }
}

// ------------------------- merged converts: x -> fp16, weights -> bf16 hi/lo
// blocks [0, XB): xcvt (N*HID/4 = 1,600,000 float4 groups); [XB, XB+WB): wcvt.
#define XB 6250     // ceil(1600000/256)
#define WB 416      // ceil(106496/256)
__global__ __launch_bounds__(256)
void cvt_k(const float* __restrict__ x, _Float16* __restrict__ xh,
           const float* __restrict__ Wa, const float* __restrict__ Wb,
           const float* __restrict__ Wh1,
           unsigned short* __restrict__ whi, unsigned short* __restrict__ wlo) {
    if (blockIdx.x < XB) {
        int i = blockIdx.x * 256 + threadIdx.x;
        if (i < 1600000) {
            float4 v = *(const float4*)&x[i * 4];
            hv4 o;
            o.x = (_Float16)v.x; o.y = (_Float16)v.y;
            o.z = (_Float16)v.z; o.w = (_Float16)v.w;
            *(hv4*)&xh[i * 4] = o;
        }
        return;
    }
    int id = (blockIdx.x - XB) * 256 + threadIdx.x;
    float v; int dst;
    if (id < 49152) {                      // 3 x 128x128 W_a
        int l = id >> 14, e = id & 16383;
        v = Wa[id];
        int n = e & 127, k = e >> 7;
        dst = (2 * l) * 16384 + n * 128 + k;
    } else if (id < 98304) {               // 3 x 128x128 W_b
        int id2 = id - 49152;
        int l = id2 >> 14, e = id2 & 16383;
        v = Wb[id2];
        int n = e & 127, k = e >> 7;
        dst = (2 * l + 1) * 16384 + n * 128 + k;
    } else if (id < 106496) {              // 128x64 W_h1
        int e = id - 98304;
        v = Wh1[e];
        int n = e & 63, k = e >> 6;
        dst = 6 * 16384 + n * 128 + k;
    } else return;
    unsigned short hi = f2bf(v);
    whi[dst] = hi;
    wlo[dst] = f2bf(v - bf2f(hi));
}

// ------------------------------------------- standalone gather-aggregate
// Pure gather kernel (no LDS, no phases): 16 nodes per 256-block, one
// quarter-wave (16 lanes x hv8 = full 256 B row) per node, unroll-4.
// z out = fp16. De-fused so gather waves saturate the miss pipeline
// (R3's standalone agg sustained 3.1 TB/s FETCH vs 1.2 fused).
__global__ __launch_bounds__(256)
void agg16_k(const _Float16* __restrict__ h_in,
             const int* __restrict__ offs, const int* __restrict__ csr,
             const float* __restrict__ eps, int layer,
             _Float16* __restrict__ z) {
    const int qw = threadIdx.x >> 4;           // 0..15
    const int l16 = threadIdx.x & 15;
    const int node = blockIdx.x * 16 + qw;
    if (node >= N_NODES) return;
    const hv8* __restrict__ h8 = (const hv8*)h_in;   // row = 16 hv8
    const float sc = 1.0f + eps[layer];
    const int beg = offs[node], end = offs[node + 1];
    float a0[8] = {0,0,0,0,0,0,0,0};
    float a1[8] = {0,0,0,0,0,0,0,0};
    int j = beg;
    for (; j + 4 <= end; j += 4) {
        int s0 = csr[j], s1 = csr[j+1], s2 = csr[j+2], s3 = csr[j+3];
        hv8 v0 = h8[(size_t)s0 * 16 + l16];
        hv8 v1 = h8[(size_t)s1 * 16 + l16];
        hv8 v2 = h8[(size_t)s2 * 16 + l16];
        hv8 v3 = h8[(size_t)s3 * 16 + l16];
#pragma unroll
        for (int e = 0; e < 8; ++e) {
            a0[e] += (float)v0[e] + (float)v2[e];
            a1[e] += (float)v1[e] + (float)v3[e];
        }
    }
    for (; j < end; ++j) {
        hv8 v = h8[(size_t)csr[j] * 16 + l16];
#pragma unroll
        for (int e = 0; e < 8; ++e) a0[e] += (float)v[e];
    }
    hv8 self = h8[(size_t)node * 16 + l16];
    hv8 o;
#pragma unroll
    for (int e = 0; e < 8; ++e)
        o[e] = (_Float16)(sc * (float)self[e] + (a0[e] + a1[e]));
    ((hv8*)z)[(size_t)node * 16 + l16] = o;
}

// ------------------------------------------------------- MLP kernel
// One block = 32 rows of z (fp16). Stage z -> LDS bf16 hi/lo, then
// z @ W_a (+ba, ReLU) -> LDS -> @ W_b (+bb, ReLU) -> fp16 h out;
// HEAD continues through W_h1 (+bh1, ReLU) and the 64->2 head -> fp32 out.
// MFMA 16x16x32 layouts (verified R3): A[m=lane&15][k=quad*8+j],
// B = Wt[n=lane&15][k], C/D col=lane&15 row=quad*4+reg.
template <bool HEAD>
__global__ __launch_bounds__(256)
void mlp_k(const _Float16* __restrict__ z_in,
           const unsigned short* __restrict__ WAhi, const unsigned short* __restrict__ WAlo,
           const float* __restrict__ ba,
           const unsigned short* __restrict__ WBhi, const unsigned short* __restrict__ WBlo,
           const float* __restrict__ bb,
           const unsigned short* __restrict__ WHhi, const unsigned short* __restrict__ WHlo,
           const float* __restrict__ bh1,
           const float* __restrict__ W2, const float* __restrict__ b2,
           void* __restrict__ outp) {
    __shared__ unsigned short Zhi[32 * 136];   // 8,704 B
    __shared__ unsigned short Zlo[32 * 136];
    const int t = threadIdx.x;
    const int wave = t >> 6, lane = t & 63;
    const int m = lane & 15, quad = lane >> 4;
    const int row0 = blockIdx.x * 32;

    // ---------- stage z -> LDS bf16 hi/lo (coalesced hv8 reads)
    {
        const int quart = lane >> 4, l16 = lane & 15;
        const hv8* __restrict__ z8 = (const hv8*)z_in;
        for (int g = 0; g < 2; ++g) {
            const int r = wave * 8 + g * 4 + quart;
            const int node = row0 + r;
            float o[8] = {0,0,0,0,0,0,0,0};
            if (node < N_NODES) {
                hv8 v = z8[(size_t)node * 16 + l16];
#pragma unroll
                for (int e = 0; e < 8; ++e) o[e] = (float)v[e];
            }
            us4 hi0, hi1, lo0, lo1;
#pragma unroll
            for (int e = 0; e < 4; ++e) {
                hi0[e] = f2bf(o[e]);     lo0[e] = f2bf(o[e]     - bf2f(hi0[e]));
                hi1[e] = f2bf(o[e + 4]); lo1[e] = f2bf(o[e + 4] - bf2f(hi1[e]));
            }
            *(us4*)&Zhi[r * 136 + l16 * 8]     = hi0;
            *(us4*)&Zhi[r * 136 + l16 * 8 + 4] = hi1;
            *(us4*)&Zlo[r * 136 + l16 * 8]     = lo0;
            *(us4*)&Zlo[r * 136 + l16 * 8 + 4] = lo1;
        }
    }

    // ---------- W_a fragments
    short8 wh[2][4], wl[2][4];
    for (int ct = 0; ct < 2; ++ct) {
        int n = wave * 32 + ct * 16 + m;
        for (int ks = 0; ks < 4; ++ks) {
            wh[ct][ks] = *(const short8*)&WAhi[n * 128 + ks * 32 + quad * 8];
            wl[ct][ks] = *(const short8*)&WAlo[n * 128 + ks * 32 + quad * 8];
        }
    }
    __syncthreads();

    // ---------- z @ W_a
    f32x4 acc[2][2];
    for (int s = 0; s < 2; ++s)
        for (int ct = 0; ct < 2; ++ct) acc[s][ct] = (f32x4){0, 0, 0, 0};
    for (int s = 0; s < 2; ++s) {
        const int r = s * 16 + m;
        for (int ks = 0; ks < 4; ++ks) {
            short8 zh = *(const short8*)&Zhi[r * 136 + ks * 32 + quad * 8];
            short8 zl = *(const short8*)&Zlo[r * 136 + ks * 32 + quad * 8];
            for (int ct = 0; ct < 2; ++ct) {
                acc[s][ct] = __builtin_amdgcn_mfma_f32_16x16x32_bf16(zh, wh[ct][ks], acc[s][ct], 0, 0, 0);
                acc[s][ct] = __builtin_amdgcn_mfma_f32_16x16x32_bf16(zh, wl[ct][ks], acc[s][ct], 0, 0, 0);
                acc[s][ct] = __builtin_amdgcn_mfma_f32_16x16x32_bf16(zl, wh[ct][ks], acc[s][ct], 0, 0, 0);
            }
        }
    }

    // ---------- W_b fragments
    for (int ct = 0; ct < 2; ++ct) {
        int n = wave * 32 + ct * 16 + m;
        for (int ks = 0; ks < 4; ++ks) {
            wh[ct][ks] = *(const short8*)&WBhi[n * 128 + ks * 32 + quad * 8];
            wl[ct][ks] = *(const short8*)&WBlo[n * 128 + ks * 32 + quad * 8];
        }
    }
    __syncthreads();

    // ---------- u = relu(acc + ba) -> LDS
    for (int s = 0; s < 2; ++s) {
        for (int ct = 0; ct < 2; ++ct) {
            int c = wave * 32 + ct * 16 + m;
            float bac = ba[c];
            for (int i = 0; i < 4; ++i) {
                int r = s * 16 + quad * 4 + i;
                float v = fmaxf(acc[s][ct][i] + bac, 0.0f);
                unsigned short hv = f2bf(v);
                Zhi[r * 136 + c] = hv;
                Zlo[r * 136 + c] = f2bf(v - bf2f(hv));
            }
        }
    }
    __syncthreads();

    // ---------- u @ W_b
    for (int s = 0; s < 2; ++s)
        for (int ct = 0; ct < 2; ++ct) acc[s][ct] = (f32x4){0, 0, 0, 0};
    for (int s = 0; s < 2; ++s) {
        const int r = s * 16 + m;
        for (int ks = 0; ks < 4; ++ks) {
            short8 zh = *(const short8*)&Zhi[r * 136 + ks * 32 + quad * 8];
            short8 zl = *(const short8*)&Zlo[r * 136 + ks * 32 + quad * 8];
            for (int ct = 0; ct < 2; ++ct) {
                acc[s][ct] = __builtin_amdgcn_mfma_f32_16x16x32_bf16(zh, wh[ct][ks], acc[s][ct], 0, 0, 0);
                acc[s][ct] = __builtin_amdgcn_mfma_f32_16x16x32_bf16(zh, wl[ct][ks], acc[s][ct], 0, 0, 0);
                acc[s][ct] = __builtin_amdgcn_mfma_f32_16x16x32_bf16(zl, wh[ct][ks], acc[s][ct], 0, 0, 0);
            }
        }
    }

    if (!HEAD) {
        _Float16* hout = (_Float16*)outp;
        for (int s = 0; s < 2; ++s) {
            for (int ct = 0; ct < 2; ++ct) {
                int c = wave * 32 + ct * 16 + m;
                float bbc = bb[c];
                for (int i = 0; i < 4; ++i) {
                    int row = row0 + s * 16 + quad * 4 + i;
                    if (row < N_NODES)
                        hout[(size_t)row * 128 + c] = (_Float16)fmaxf(acc[s][ct][i] + bbc, 0.0f);
                }
            }
        }
    } else {
        // ---------- W_h1 fragments
        short8 hh[4], hl[4];
        {
            int n = wave * 16 + m;
            for (int ks = 0; ks < 4; ++ks) {
                hh[ks] = *(const short8*)&WHhi[n * 128 + ks * 32 + quad * 8];
                hl[ks] = *(const short8*)&WHlo[n * 128 + ks * 32 + quad * 8];
            }
        }
        __syncthreads();

        for (int s = 0; s < 2; ++s) {
            for (int ct = 0; ct < 2; ++ct) {
                int c = wave * 32 + ct * 16 + m;
                float bbc = bb[c];
                for (int i = 0; i < 4; ++i) {
                    int r = s * 16 + quad * 4 + i;
                    float v = fmaxf(acc[s][ct][i] + bbc, 0.0f);
                    unsigned short hv = f2bf(v);
                    Zhi[r * 136 + c] = hv;
                    Zlo[r * 136 + c] = f2bf(v - bf2f(hv));
                }
            }
        }
        __syncthreads();

        // ---------- h @ W_h1 (128 -> 64)
        f32x4 a3[2];
        for (int s = 0; s < 2; ++s) a3[s] = (f32x4){0, 0, 0, 0};
        for (int s = 0; s < 2; ++s) {
            const int r = s * 16 + m;
            for (int ks = 0; ks < 4; ++ks) {
                short8 zh = *(const short8*)&Zhi[r * 136 + ks * 32 + quad * 8];
                short8 zl = *(const short8*)&Zlo[r * 136 + ks * 32 + quad * 8];
                a3[s] = __builtin_amdgcn_mfma_f32_16x16x32_bf16(zh, hh[ks], a3[s], 0, 0, 0);
                a3[s] = __builtin_amdgcn_mfma_f32_16x16x32_bf16(zh, hl[ks], a3[s], 0, 0, 0);
                a3[s] = __builtin_amdgcn_mfma_f32_16x16x32_bf16(zl, hh[ks], a3[s], 0, 0, 0);
            }
        }
        __syncthreads();

        float* Hid = (float*)Zhi;   // 32 x 68 fp32 (fits)
        for (int s = 0; s < 2; ++s) {
            int c = wave * 16 + m;
            float bc = bh1[c];
            for (int i = 0; i < 4; ++i) {
                int r = s * 16 + quad * 4 + i;
                Hid[r * 68 + c] = fmaxf(a3[s][i] + bc, 0.0f);
            }
        }
        __syncthreads();

        if (t < 64) {
            float* outF = (float*)outp;
            int r = t >> 1, col = t & 1;
            float a = b2[col];
#pragma unroll
            for (int j = 0; j < 64; ++j) a += Hid[r * 68 + j] * W2[j * 2 + col];
            int node = row0 + r;
            if (node < N_NODES) outF[(size_t)node * 2 + col] = a;
        }
    }
}

// ------------------------------------------------------------------ launch

extern "C" void kernel_launch(void* const* d_in, const int* in_sizes, int n_in,
                              void* d_out, int out_size, void* d_ws, size_t ws_size,
                              hipStream_t stream) {
    const float* x    = (const float*)d_in[0];
    const int*   ei   = (const int*)d_in[1];
    const float* eps  = (const float*)d_in[2];
    const float* W_a  = (const float*)d_in[3];
    const float* b_a  = (const float*)d_in[4];
    const float* W_b  = (const float*)d_in[5];
    const float* b_b  = (const float*)d_in[6];
    const float* W_h1 = (const float*)d_in[7];
    const float* b_h1 = (const float*)d_in[8];
    const float* W_h2 = (const float*)d_in[9];
    const float* b_h2 = (const float*)d_in[10];
    float* out = (float*)d_out;

    const int N = N_NODES, E = N_EDGES;
    const int* src = ei;
    const int* dst = ei + E;

    char* ws = (char*)d_ws;
    size_t off = 0;
    auto carve = [&](size_t bytes) {
        char* p = ws + off;
        off = (off + bytes + 255) & ~(size_t)255;
        return p;
    };
    _Float16* xh   = (_Float16*)carve((size_t)N * HID * sizeof(_Float16));
    _Float16* zb   = (_Float16*)carve((size_t)N * HID * sizeof(_Float16));
    _Float16* bufA = (_Float16*)carve((size_t)N * HID * sizeof(_Float16));
    _Float16* bufB = (_Float16*)carve((size_t)N * HID * sizeof(_Float16));
    int*   tmp    = (int*)carve((size_t)E * sizeof(int));
    int*   csr    = (int*)carve((size_t)E * sizeof(int));
    int*   offs   = (int*)carve((size_t)(N + 1) * sizeof(int));
    int*   bh     = (int*)carve((size_t)NB * NBLK * sizeof(int));
    int*   bhs    = (int*)carve((size_t)NB * NBLK * sizeof(int));
    int*   bsum   = (int*)carve(64 * sizeof(int));
    unsigned short* whi = (unsigned short*)carve(7 * 16384 * sizeof(unsigned short));
    unsigned short* wlo = (unsigned short*)carve(7 * 16384 * sizeof(unsigned short));
    (void)ws_size;

    // ---- CSR build: streaming counting sort (LDS atomics only)
    const int M = NB * NBLK;                     // 62,560
    const int SB = (M + 2047) / 2048;            // 31 scan blocks
    hist_k<<<NBLK, 256, 0, stream>>>(dst, bh, E);
    scanA_k<<<SB, 256, 0, stream>>>(bh, bsum, M);
    scanC_k<<<SB, 256, 0, stream>>>(bh, bsum, bhs, M, SB);
    scatter_k<<<NBLK, 256, 0, stream>>>(src, dst, bhs, tmp, E);
    bucket_k<<<NB, 256, 0, stream>>>(tmp, bhs, offs, csr, E, N);

    // ---- merged input + weight conversion
    cvt_k<<<XB + WB, 256, 0, stream>>>(x, xh, W_a, W_b, W_h1, whi, wlo);

    const int agg_grid = (N + 15) / 16;
    const int mlp_grid = (N + 31) / 32;
    #define WSLOT(s) (whi + (s) * 16384), (wlo + (s) * 16384)
    #define NOHEAD (const unsigned short*)nullptr, (const unsigned short*)nullptr, \
                   (const float*)nullptr, (const float*)nullptr, (const float*)nullptr

    // layer 0
    agg16_k<<<agg_grid, 256, 0, stream>>>(xh, offs, csr, eps, 0, zb);
    mlp_k<false><<<mlp_grid, 256, 0, stream>>>(zb, WSLOT(0), b_a + 0 * 128,
        WSLOT(1), b_b + 0 * 128, NOHEAD, (void*)bufA);
    // layer 1
    agg16_k<<<agg_grid, 256, 0, stream>>>(bufA, offs, csr, eps, 1, zb);
    mlp_k<false><<<mlp_grid, 256, 0, stream>>>(zb, WSLOT(2), b_a + 1 * 128,
        WSLOT(3), b_b + 1 * 128, NOHEAD, (void*)bufB);
    // layer 2 + head
    agg16_k<<<agg_grid, 256, 0, stream>>>(bufB, offs, csr, eps, 2, zb);
    mlp_k<true><<<mlp_grid, 256, 0, stream>>>(zb, WSLOT(4), b_a + 2 * 128,
        WSLOT(5), b_b + 2 * 128, WSLOT(6), b_h1, W_h2, b_h2, (void*)out);
}

// Round 11
// 324.233 us; speedup vs baseline: 1.3940x; 1.0128x over previous
//
#include <hip/hip_runtime.h>
#include <hip/hip_bf16.h>

#define N_NODES 50000
#define N_EDGES 800000
#define HID 128

#define NB 391      // dst buckets: dst>>7, 128 nodes each
#define NBLK 160    // histogram/scatter blocks
#define EPB 5000    // edges per block (NBLK*EPB == N_EDGES)

typedef __attribute__((ext_vector_type(8))) short short8;     // 8 bf16 (4 VGPR)
typedef __attribute__((ext_vector_type(4))) float f32x4;      // MFMA acc
typedef __attribute__((ext_vector_type(4))) unsigned short us4;
typedef _Float16 hv8 __attribute__((ext_vector_type(8)));     // 8 fp16 (16 B)
typedef _Float16 hv4 __attribute__((ext_vector_type(4)));     // 4 fp16 (8 B)

__device__ __forceinline__ unsigned short f2bf(float v) {
    union { float f; unsigned u; } x; x.f = v;
    unsigned r = x.u + 0x7fff + ((x.u >> 16) & 1);   // RTN-even
    return (unsigned short)(r >> 16);
}
__device__ __forceinline__ float bf2f(unsigned short b) {
    union { unsigned u; float f; } x; x.u = ((unsigned)b) << 16;
    return x.f;
}

// ----------------------------- CSR build: streaming 2-level counting sort

__global__ __launch_bounds__(256)
void hist_k(const int* __restrict__ dst, int* __restrict__ bh, int E) {
    __shared__ int h[NB];
    for (int i = threadIdx.x; i < NB; i += 256) h[i] = 0;
    __syncthreads();
    const int base = blockIdx.x * EPB;
    const int end = min(base + EPB, E);
    for (int i = base + threadIdx.x; i < end; i += 256)
        atomicAdd(&h[dst[i] >> 7], 1);
    __syncthreads();
    for (int i = threadIdx.x; i < NB; i += 256)
        bh[i * NBLK + blockIdx.x] = h[i];
}

// scanA: per-block sums of 2048-int chunks -> bsum[31]
__global__ __launch_bounds__(256)
void scanA_k(const int* __restrict__ in, int* __restrict__ bsum, int n) {
    const int t = threadIdx.x, base = blockIdx.x * 2048 + t * 8;
    int s = 0;
#pragma unroll
    for (int k = 0; k < 8; ++k) s += (base + k < n) ? in[base + k] : 0;
    __shared__ int sh[256];
    sh[t] = s;
    __syncthreads();
    for (int o = 128; o > 0; o >>= 1) {
        if (t < o) sh[t] += sh[t + o];
        __syncthreads();
    }
    if (t == 0) bsum[blockIdx.x] = sh[0];
}

// scanC: each block self-scans the (<=64) partials, then local scan + write
__global__ __launch_bounds__(256)
void scanC_k(const int* __restrict__ in, const int* __restrict__ bsum,
             int* __restrict__ out, int n, int B) {
    const int t = threadIdx.x, base = blockIdx.x * 2048 + t * 8;
    __shared__ int blockoff;
    if (t == 0) {
        int p = 0;
        for (int i = 0; i < blockIdx.x; ++i) p += bsum[i];   // B<=64, trivial
        blockoff = p;
    }
    int v[8]; int s = 0;
#pragma unroll
    for (int k = 0; k < 8; ++k) { v[k] = (base + k < n) ? in[base + k] : 0; s += v[k]; }
    __shared__ int sh[256];
    sh[t] = s;
    __syncthreads();
    for (int o = 1; o < 256; o <<= 1) {
        int u = (t >= o) ? sh[t - o] : 0;
        __syncthreads();
        sh[t] += u;
        __syncthreads();
    }
    int run = ((t == 0) ? 0 : sh[t - 1]) + blockoff;
#pragma unroll
    for (int k = 0; k < 8; ++k) {
        if (base + k < n) out[base + k] = run;
        run += v[k];
    }
}

// scatter: edges -> bucket-segmented tmp (packed: src<<7 | dst&127)
__global__ __launch_bounds__(256)
void scatter_k(const int* __restrict__ src, const int* __restrict__ dst,
               const int* __restrict__ bhs, int* __restrict__ tmp, int E) {
    __shared__ int cur[NB];
    for (int i = threadIdx.x; i < NB; i += 256) cur[i] = bhs[i * NBLK + blockIdx.x];
    __syncthreads();
    const int base = blockIdx.x * EPB;
    const int end = min(base + EPB, E);
    for (int i = base + threadIdx.x; i < end; i += 256) {
        int d = dst[i];
        int p = atomicAdd(&cur[d >> 7], 1);
        tmp[p] = (src[i] << 7) | (d & 127);
    }
}

// bucket: one block per bucket — 128-counter local sort; writes offs + csr
__global__ __launch_bounds__(256)
void bucket_k(const int* __restrict__ tmp, const int* __restrict__ bhs,
              int* __restrict__ offs, int* __restrict__ csr, int E, int N) {
    const int b = blockIdx.x;
    const int t = threadIdx.x;
    __shared__ int hist[128], excl[128], cur[128];
    const int bstart = bhs[b * NBLK];
    const int bend = (b + 1 < NB) ? bhs[(b + 1) * NBLK] : E;
    if (t < 128) hist[t] = 0;
    __syncthreads();
    for (int i = bstart + t; i < bend; i += 256)
        atomicAdd(&hist[tmp[i] & 127], 1);
    __syncthreads();
    if (t < 128) excl[t] = hist[t];
    __syncthreads();
    for (int o = 1; o < 128; o <<= 1) {
        int u = (t < 128 && t >= o) ? excl[t - o] : 0;
        __syncthreads();
        if (t < 128) excl[t] += u;
        __syncthreads();
    }
    const int node0 = b * 128;
    if (t < 128) {
        int base = bstart + ((t == 0) ? 0 : excl[t - 1]);
        if (node0 + t < N) offs[node0 + t] = base;
        cur[t] = base;
    }
    if (b == 0 && t == 0) offs[N] = E;
    __syncthreads();
    for (int i = bstart + t; i < bend; i += 256) {
        int e = tmp[i];
        int p = atomicAdd(&cur[e & 127], 1);
        csr[p] = e >> 7;
    }
}

// ------------------------- merged converts: x -> fp16, weights -> bf16 hi/lo
// blocks [0, XB): xcvt (N*HID/4 = 1,600,000 float4 groups); [XB, XB+WB): wcvt.
#define XB 6250     // ceil(1600000/256)
#define WB 416      // ceil(106496/256)
__global__ __launch_bounds__(256)
void cvt_k(const float* __restrict__ x, _Float16* __restrict__ xh,
           const float* __restrict__ Wa, const float* __restrict__ Wb,
           const float* __restrict__ Wh1,
           unsigned short* __restrict__ whi, unsigned short* __restrict__ wlo) {
    if (blockIdx.x < XB) {
        int i = blockIdx.x * 256 + threadIdx.x;
        if (i < 1600000) {
            float4 v = *(const float4*)&x[i * 4];
            hv4 o;
            o.x = (_Float16)v.x; o.y = (_Float16)v.y;
            o.z = (_Float16)v.z; o.w = (_Float16)v.w;
            *(hv4*)&xh[i * 4] = o;
        }
        return;
    }
    int id = (blockIdx.x - XB) * 256 + threadIdx.x;
    float v; int dst;
    if (id < 49152) {                      // 3 x 128x128 W_a
        int l = id >> 14, e = id & 16383;
        v = Wa[id];
        int n = e & 127, k = e >> 7;
        dst = (2 * l) * 16384 + n * 128 + k;
    } else if (id < 98304) {               // 3 x 128x128 W_b
        int id2 = id - 49152;
        int l = id2 >> 14, e = id2 & 16383;
        v = Wb[id2];
        int n = e & 127, k = e >> 7;
        dst = (2 * l + 1) * 16384 + n * 128 + k;
    } else if (id < 106496) {              // 128x64 W_h1
        int e = id - 98304;
        v = Wh1[e];
        int n = e & 63, k = e >> 6;
        dst = 6 * 16384 + n * 128 + k;
    } else return;
    unsigned short hi = f2bf(v);
    whi[dst] = hi;
    wlo[dst] = f2bf(v - bf2f(hi));
}

// ------------------------------------------- standalone gather-aggregate
// Pure gather kernel (no LDS, no phases): 16 nodes per 256-block, one
// quarter-wave (16 lanes x hv8 = full 256 B row) per node, unroll-4.
__global__ __launch_bounds__(256)
void agg16_k(const _Float16* __restrict__ h_in,
             const int* __restrict__ offs, const int* __restrict__ csr,
             const float* __restrict__ eps, int layer,
             _Float16* __restrict__ z) {
    const int qw = threadIdx.x >> 4;           // 0..15
    const int l16 = threadIdx.x & 15;
    const int node = blockIdx.x * 16 + qw;
    if (node >= N_NODES) return;
    const hv8* __restrict__ h8 = (const hv8*)h_in;   // row = 16 hv8
    const float sc = 1.0f + eps[layer];
    const int beg = offs[node], end = offs[node + 1];
    float a0[8] = {0,0,0,0,0,0,0,0};
    float a1[8] = {0,0,0,0,0,0,0,0};
    int j = beg;
    for (; j + 4 <= end; j += 4) {
        int s0 = csr[j], s1 = csr[j+1], s2 = csr[j+2], s3 = csr[j+3];
        hv8 v0 = h8[(size_t)s0 * 16 + l16];
        hv8 v1 = h8[(size_t)s1 * 16 + l16];
        hv8 v2 = h8[(size_t)s2 * 16 + l16];
        hv8 v3 = h8[(size_t)s3 * 16 + l16];
#pragma unroll
        for (int e = 0; e < 8; ++e) {
            a0[e] += (float)v0[e] + (float)v2[e];
            a1[e] += (float)v1[e] + (float)v3[e];
        }
    }
    for (; j < end; ++j) {
        hv8 v = h8[(size_t)csr[j] * 16 + l16];
#pragma unroll
        for (int e = 0; e < 8; ++e) a0[e] += (float)v[e];
    }
    hv8 self = h8[(size_t)node * 16 + l16];
    hv8 o;
#pragma unroll
    for (int e = 0; e < 8; ++e)
        o[e] = (_Float16)(sc * (float)self[e] + (a0[e] + a1[e]));
    ((hv8*)z)[(size_t)node * 16 + l16] = o;
}

// ------------------------------------------------------- MLP kernel (v2)
// One block = 32 rows. W fragments STREAMED per k-step (ks-outer,
// #pragma unroll 1) so only 16 W regs live instead of 64 — R10's counters
// showed the W-resident version eats ~148 unified VGPR+AGPR regs ->
// 12 waves/CU -> 21% occupancy, latency-bound at 42.8 us.
// FP accumulate order per acc element unchanged (ks ascending).
// MFMA 16x16x32 layouts (verified R3): A[m=lane&15][k=quad*8+j],
// B = Wt[n=lane&15][k], C/D col=lane&15 row=quad*4+reg.
template <bool HEAD>
__global__ __launch_bounds__(256)
void mlp_k(const _Float16* __restrict__ z_in,
           const unsigned short* __restrict__ WAhi, const unsigned short* __restrict__ WAlo,
           const float* __restrict__ ba,
           const unsigned short* __restrict__ WBhi, const unsigned short* __restrict__ WBlo,
           const float* __restrict__ bb,
           const unsigned short* __restrict__ WHhi, const unsigned short* __restrict__ WHlo,
           const float* __restrict__ bh1,
           const float* __restrict__ W2, const float* __restrict__ b2,
           void* __restrict__ outp) {
    __shared__ unsigned short Zhi[32 * 136];   // 8,704 B
    __shared__ unsigned short Zlo[32 * 136];
    const int t = threadIdx.x;
    const int wave = t >> 6, lane = t & 63;
    const int m = lane & 15, quad = lane >> 4;
    const int row0 = blockIdx.x * 32;

    // ---------- stage z -> LDS bf16 hi/lo (coalesced hv8 reads)
    {
        const int quart = lane >> 4, l16 = lane & 15;
        const hv8* __restrict__ z8 = (const hv8*)z_in;
        for (int g = 0; g < 2; ++g) {
            const int r = wave * 8 + g * 4 + quart;
            const int node = row0 + r;
            float o[8] = {0,0,0,0,0,0,0,0};
            if (node < N_NODES) {
                hv8 v = z8[(size_t)node * 16 + l16];
#pragma unroll
                for (int e = 0; e < 8; ++e) o[e] = (float)v[e];
            }
            us4 hi0, hi1, lo0, lo1;
#pragma unroll
            for (int e = 0; e < 4; ++e) {
                hi0[e] = f2bf(o[e]);     lo0[e] = f2bf(o[e]     - bf2f(hi0[e]));
                hi1[e] = f2bf(o[e + 4]); lo1[e] = f2bf(o[e + 4] - bf2f(hi1[e]));
            }
            *(us4*)&Zhi[r * 136 + l16 * 8]     = hi0;
            *(us4*)&Zhi[r * 136 + l16 * 8 + 4] = hi1;
            *(us4*)&Zlo[r * 136 + l16 * 8]     = lo0;
            *(us4*)&Zlo[r * 136 + l16 * 8 + 4] = lo1;
        }
    }
    __syncthreads();

    const int n0 = (wave * 32 + m) * 128 + quad * 8;        // W row base, ct=0
    const int n1 = (wave * 32 + 16 + m) * 128 + quad * 8;   // ct=1

    // ---------- phase 2: z @ W_a (W streamed per ks)
    f32x4 acc[2][2];
    for (int s = 0; s < 2; ++s)
        for (int ct = 0; ct < 2; ++ct) acc[s][ct] = (f32x4){0, 0, 0, 0};
#pragma unroll 1
    for (int ks = 0; ks < 4; ++ks) {
        const int wo = ks * 32;
        short8 wh0 = *(const short8*)&WAhi[n0 + wo];
        short8 wl0 = *(const short8*)&WAlo[n0 + wo];
        short8 wh1 = *(const short8*)&WAhi[n1 + wo];
        short8 wl1 = *(const short8*)&WAlo[n1 + wo];
#pragma unroll
        for (int s = 0; s < 2; ++s) {
            const int r = s * 16 + m;
            short8 zh = *(const short8*)&Zhi[r * 136 + wo + quad * 8];
            short8 zl = *(const short8*)&Zlo[r * 136 + wo + quad * 8];
            acc[s][0] = __builtin_amdgcn_mfma_f32_16x16x32_bf16(zh, wh0, acc[s][0], 0, 0, 0);
            acc[s][0] = __builtin_amdgcn_mfma_f32_16x16x32_bf16(zh, wl0, acc[s][0], 0, 0, 0);
            acc[s][0] = __builtin_amdgcn_mfma_f32_16x16x32_bf16(zl, wh0, acc[s][0], 0, 0, 0);
            acc[s][1] = __builtin_amdgcn_mfma_f32_16x16x32_bf16(zh, wh1, acc[s][1], 0, 0, 0);
            acc[s][1] = __builtin_amdgcn_mfma_f32_16x16x32_bf16(zh, wl1, acc[s][1], 0, 0, 0);
            acc[s][1] = __builtin_amdgcn_mfma_f32_16x16x32_bf16(zl, wh1, acc[s][1], 0, 0, 0);
        }
    }
    __syncthreads();   // all z reads done; safe to overwrite LDS

    // ---------- u = relu(acc + ba) -> LDS
    for (int s = 0; s < 2; ++s) {
        for (int ct = 0; ct < 2; ++ct) {
            int c = wave * 32 + ct * 16 + m;
            float bac = ba[c];
            for (int i = 0; i < 4; ++i) {
                int r = s * 16 + quad * 4 + i;
                float v = fmaxf(acc[s][ct][i] + bac, 0.0f);
                unsigned short hv = f2bf(v);
                Zhi[r * 136 + c] = hv;
                Zlo[r * 136 + c] = f2bf(v - bf2f(hv));
            }
        }
    }
    __syncthreads();

    // ---------- phase 3: u @ W_b (W streamed per ks)
    for (int s = 0; s < 2; ++s)
        for (int ct = 0; ct < 2; ++ct) acc[s][ct] = (f32x4){0, 0, 0, 0};
#pragma unroll 1
    for (int ks = 0; ks < 4; ++ks) {
        const int wo = ks * 32;
        short8 wh0 = *(const short8*)&WBhi[n0 + wo];
        short8 wl0 = *(const short8*)&WBlo[n0 + wo];
        short8 wh1 = *(const short8*)&WBhi[n1 + wo];
        short8 wl1 = *(const short8*)&WBlo[n1 + wo];
#pragma unroll
        for (int s = 0; s < 2; ++s) {
            const int r = s * 16 + m;
            short8 zh = *(const short8*)&Zhi[r * 136 + wo + quad * 8];
            short8 zl = *(const short8*)&Zlo[r * 136 + wo + quad * 8];
            acc[s][0] = __builtin_amdgcn_mfma_f32_16x16x32_bf16(zh, wh0, acc[s][0], 0, 0, 0);
            acc[s][0] = __builtin_amdgcn_mfma_f32_16x16x32_bf16(zh, wl0, acc[s][0], 0, 0, 0);
            acc[s][0] = __builtin_amdgcn_mfma_f32_16x16x32_bf16(zl, wh0, acc[s][0], 0, 0, 0);
            acc[s][1] = __builtin_amdgcn_mfma_f32_16x16x32_bf16(zh, wh1, acc[s][1], 0, 0, 0);
            acc[s][1] = __builtin_amdgcn_mfma_f32_16x16x32_bf16(zh, wl1, acc[s][1], 0, 0, 0);
            acc[s][1] = __builtin_amdgcn_mfma_f32_16x16x32_bf16(zl, wh1, acc[s][1], 0, 0, 0);
        }
    }

    if (!HEAD) {
        _Float16* hout = (_Float16*)outp;
        for (int s = 0; s < 2; ++s) {
            for (int ct = 0; ct < 2; ++ct) {
                int c = wave * 32 + ct * 16 + m;
                float bbc = bb[c];
                for (int i = 0; i < 4; ++i) {
                    int row = row0 + s * 16 + quad * 4 + i;
                    if (row < N_NODES)
                        hout[(size_t)row * 128 + c] = (_Float16)fmaxf(acc[s][ct][i] + bbc, 0.0f);
                }
            }
        }
    } else {
        __syncthreads();   // all u reads done; safe to overwrite LDS

        // ---------- h = relu(acc + bb) -> LDS
        for (int s = 0; s < 2; ++s) {
            for (int ct = 0; ct < 2; ++ct) {
                int c = wave * 32 + ct * 16 + m;
                float bbc = bb[c];
                for (int i = 0; i < 4; ++i) {
                    int r = s * 16 + quad * 4 + i;
                    float v = fmaxf(acc[s][ct][i] + bbc, 0.0f);
                    unsigned short hv = f2bf(v);
                    Zhi[r * 136 + c] = hv;
                    Zlo[r * 136 + c] = f2bf(v - bf2f(hv));
                }
            }
        }
        __syncthreads();

        // ---------- phase 4: h @ W_h1 (128 -> 64), W streamed per ks
        const int nh = (wave * 16 + m) * 128 + quad * 8;
        f32x4 a3[2];
        for (int s = 0; s < 2; ++s) a3[s] = (f32x4){0, 0, 0, 0};
#pragma unroll 1
        for (int ks = 0; ks < 4; ++ks) {
            const int wo = ks * 32;
            short8 hh = *(const short8*)&WHhi[nh + wo];
            short8 hl = *(const short8*)&WHlo[nh + wo];
#pragma unroll
            for (int s = 0; s < 2; ++s) {
                const int r = s * 16 + m;
                short8 zh = *(const short8*)&Zhi[r * 136 + wo + quad * 8];
                short8 zl = *(const short8*)&Zlo[r * 136 + wo + quad * 8];
                a3[s] = __builtin_amdgcn_mfma_f32_16x16x32_bf16(zh, hh, a3[s], 0, 0, 0);
                a3[s] = __builtin_amdgcn_mfma_f32_16x16x32_bf16(zh, hl, a3[s], 0, 0, 0);
                a3[s] = __builtin_amdgcn_mfma_f32_16x16x32_bf16(zl, hh, a3[s], 0, 0, 0);
            }
        }
        __syncthreads();   // phase-4 reads done; reuse LDS as fp32

        float* Hid = (float*)Zhi;   // 32 x 68 fp32 (fits in Zhi)
        for (int s = 0; s < 2; ++s) {
            int c = wave * 16 + m;
            float bc = bh1[c];
            for (int i = 0; i < 4; ++i) {
                int r = s * 16 + quad * 4 + i;
                Hid[r * 68 + c] = fmaxf(a3[s][i] + bc, 0.0f);
            }
        }
        __syncthreads();

        // ---------- phase 5: hid @ W_h2 (64 -> 2) + b2 -> out
        // all 256 threads: pair = t>>2 (r,col), seg = t&3 sums 16 j's
        float* Red = (float*)Zlo;   // 256 floats, Zlo free after phase 4
        {
            int pair = t >> 2, seg = t & 3;
            int r = pair >> 1, col = pair & 1;
            float p = 0.0f;
#pragma unroll
            for (int j = seg * 16; j < seg * 16 + 16; ++j)
                p += Hid[r * 68 + j] * W2[j * 2 + col];
            Red[t] = p;
        }
        __syncthreads();
        if (t < 64) {
            float* outF = (float*)outp;
            int r = t >> 1, col = t & 1;
            float a = b2[col] + ((Red[t * 4] + Red[t * 4 + 1]) + (Red[t * 4 + 2] + Red[t * 4 + 3]));
            int node = row0 + r;
            if (node < N_NODES) outF[(size_t)node * 2 + col] = a;
        }
    }
}

// ------------------------------------------------------------------ launch

extern "C" void kernel_launch(void* const* d_in, const int* in_sizes, int n_in,
                              void* d_out, int out_size, void* d_ws, size_t ws_size,
                              hipStream_t stream) {
    const float* x    = (const float*)d_in[0];
    const int*   ei   = (const int*)d_in[1];
    const float* eps  = (const float*)d_in[2];
    const float* W_a  = (const float*)d_in[3];
    const float* b_a  = (const float*)d_in[4];
    const float* W_b  = (const float*)d_in[5];
    const float* b_b  = (const float*)d_in[6];
    const float* W_h1 = (const float*)d_in[7];
    const float* b_h1 = (const float*)d_in[8];
    const float* W_h2 = (const float*)d_in[9];
    const float* b_h2 = (const float*)d_in[10];
    float* out = (float*)d_out;

    const int N = N_NODES, E = N_EDGES;
    const int* src = ei;
    const int* dst = ei + E;

    char* ws = (char*)d_ws;
    size_t off = 0;
    auto carve = [&](size_t bytes) {
        char* p = ws + off;
        off = (off + bytes + 255) & ~(size_t)255;
        return p;
    };
    _Float16* xh   = (_Float16*)carve((size_t)N * HID * sizeof(_Float16));
    _Float16* zb   = (_Float16*)carve((size_t)N * HID * sizeof(_Float16));
    _Float16* bufA = (_Float16*)carve((size_t)N * HID * sizeof(_Float16));
    _Float16* bufB = (_Float16*)carve((size_t)N * HID * sizeof(_Float16));
    int*   tmp    = (int*)carve((size_t)E * sizeof(int));
    int*   csr    = (int*)carve((size_t)E * sizeof(int));
    int*   offs   = (int*)carve((size_t)(N + 1) * sizeof(int));
    int*   bh     = (int*)carve((size_t)NB * NBLK * sizeof(int));
    int*   bhs    = (int*)carve((size_t)NB * NBLK * sizeof(int));
    int*   bsum   = (int*)carve(64 * sizeof(int));
    unsigned short* whi = (unsigned short*)carve(7 * 16384 * sizeof(unsigned short));
    unsigned short* wlo = (unsigned short*)carve(7 * 16384 * sizeof(unsigned short));
    (void)ws_size;

    // ---- CSR build: streaming counting sort (LDS atomics only)
    const int M = NB * NBLK;                     // 62,560
    const int SB = (M + 2047) / 2048;            // 31 scan blocks
    hist_k<<<NBLK, 256, 0, stream>>>(dst, bh, E);
    scanA_k<<<SB, 256, 0, stream>>>(bh, bsum, M);
    scanC_k<<<SB, 256, 0, stream>>>(bh, bsum, bhs, M, SB);
    scatter_k<<<NBLK, 256, 0, stream>>>(src, dst, bhs, tmp, E);
    bucket_k<<<NB, 256, 0, stream>>>(tmp, bhs, offs, csr, E, N);

    // ---- merged input + weight conversion
    cvt_k<<<XB + WB, 256, 0, stream>>>(x, xh, W_a, W_b, W_h1, whi, wlo);

    const int agg_grid = (N + 15) / 16;
    const int mlp_grid = (N + 31) / 32;
    #define WSLOT(s) (whi + (s) * 16384), (wlo + (s) * 16384)
    #define NOHEAD (const unsigned short*)nullptr, (const unsigned short*)nullptr, \
                   (const float*)nullptr, (const float*)nullptr, (const float*)nullptr

    // layer 0
    agg16_k<<<agg_grid, 256, 0, stream>>>(xh, offs, csr, eps, 0, zb);
    mlp_k<false><<<mlp_grid, 256, 0, stream>>>(zb, WSLOT(0), b_a + 0 * 128,
        WSLOT(1), b_b + 0 * 128, NOHEAD, (void*)bufA);
    // layer 1
    agg16_k<<<agg_grid, 256, 0, stream>>>(bufA, offs, csr, eps, 1, zb);
    mlp_k<false><<<mlp_grid, 256, 0, stream>>>(zb, WSLOT(2), b_a + 1 * 128,
        WSLOT(3), b_b + 1 * 128, NOHEAD, (void*)bufB);
    // layer 2 + head
    agg16_k<<<agg_grid, 256, 0, stream>>>(bufB, offs, csr, eps, 2, zb);
    mlp_k<true><<<mlp_grid, 256, 0, stream>>>(zb, WSLOT(4), b_a + 2 * 128,
        WSLOT(5), b_b + 2 * 128, WSLOT(6), b_h1, W_h2, b_h2, (void*)out);
}

// Round 12
// 275.789 us; speedup vs baseline: 1.6389x; 1.1757x over previous
//
#include <hip/hip_runtime.h>
#include <hip/hip_bf16.h>

#define N_NODES 50000
#define N_EDGES 800000
#define HID 128

#define NB 391      // dst buckets: dst>>7, 128 nodes each
#define NBLK 160    // histogram/scatter blocks
#define EPB 5000    // edges per block (NBLK*EPB == N_EDGES)

typedef __attribute__((ext_vector_type(8))) short short8;     // 8 bf16 (4 VGPR)
typedef __attribute__((ext_vector_type(4))) float f32x4;      // MFMA acc
typedef __attribute__((ext_vector_type(4))) unsigned short us4;
typedef _Float16 hv8 __attribute__((ext_vector_type(8)));     // 8 fp16 (16 B)
typedef _Float16 hv4 __attribute__((ext_vector_type(4)));     // 4 fp16 (8 B)

__device__ __forceinline__ unsigned short f2bf(float v) {
    union { float f; unsigned u; } x; x.f = v;
    unsigned r = x.u + 0x7fff + ((x.u >> 16) & 1);   // RTN-even
    return (unsigned short)(r >> 16);
}
__device__ __forceinline__ float bf2f(unsigned short b) {
    union { unsigned u; float f; } x; x.u = ((unsigned)b) << 16;
    return x.f;
}

// ----------------------------- CSR build: streaming 2-level counting sort

__global__ __launch_bounds__(256)
void hist_k(const int* __restrict__ dst, int* __restrict__ bh, int E) {
    __shared__ int h[NB];
    for (int i = threadIdx.x; i < NB; i += 256) h[i] = 0;
    __syncthreads();
    const int base = blockIdx.x * EPB;
    const int end = min(base + EPB, E);
    for (int i = base + threadIdx.x; i < end; i += 256)
        atomicAdd(&h[dst[i] >> 7], 1);
    __syncthreads();
    for (int i = threadIdx.x; i < NB; i += 256)
        bh[i * NBLK + blockIdx.x] = h[i];
}

// scanA: per-block sums of 2048-int chunks -> bsum[31]
__global__ __launch_bounds__(256)
void scanA_k(const int* __restrict__ in, int* __restrict__ bsum, int n) {
    const int t = threadIdx.x, base = blockIdx.x * 2048 + t * 8;
    int s = 0;
#pragma unroll
    for (int k = 0; k < 8; ++k) s += (base + k < n) ? in[base + k] : 0;
    __shared__ int sh[256];
    sh[t] = s;
    __syncthreads();
    for (int o = 128; o > 0; o >>= 1) {
        if (t < o) sh[t] += sh[t + o];
        __syncthreads();
    }
    if (t == 0) bsum[blockIdx.x] = sh[0];
}

// scanC: each block self-scans the (<=64) partials, then local scan + write
__global__ __launch_bounds__(256)
void scanC_k(const int* __restrict__ in, const int* __restrict__ bsum,
             int* __restrict__ out, int n, int B) {
    const int t = threadIdx.x, base = blockIdx.x * 2048 + t * 8;
    __shared__ int blockoff;
    if (t == 0) {
        int p = 0;
        for (int i = 0; i < blockIdx.x; ++i) p += bsum[i];   // B<=64, trivial
        blockoff = p;
    }
    int v[8]; int s = 0;
#pragma unroll
    for (int k = 0; k < 8; ++k) { v[k] = (base + k < n) ? in[base + k] : 0; s += v[k]; }
    __shared__ int sh[256];
    sh[t] = s;
    __syncthreads();
    for (int o = 1; o < 256; o <<= 1) {
        int u = (t >= o) ? sh[t - o] : 0;
        __syncthreads();
        sh[t] += u;
        __syncthreads();
    }
    int run = ((t == 0) ? 0 : sh[t - 1]) + blockoff;
#pragma unroll
    for (int k = 0; k < 8; ++k) {
        if (base + k < n) out[base + k] = run;
        run += v[k];
    }
}

// scatter: edges -> bucket-segmented tmp (packed: src<<7 | dst&127)
__global__ __launch_bounds__(256)
void scatter_k(const int* __restrict__ src, const int* __restrict__ dst,
               const int* __restrict__ bhs, int* __restrict__ tmp, int E) {
    __shared__ int cur[NB];
    for (int i = threadIdx.x; i < NB; i += 256) cur[i] = bhs[i * NBLK + blockIdx.x];
    __syncthreads();
    const int base = blockIdx.x * EPB;
    const int end = min(base + EPB, E);
    for (int i = base + threadIdx.x; i < end; i += 256) {
        int d = dst[i];
        int p = atomicAdd(&cur[d >> 7], 1);
        tmp[p] = (src[i] << 7) | (d & 127);
    }
}

// bucket: one block per bucket — 128-counter local sort; writes offs + csr
__global__ __launch_bounds__(256)
void bucket_k(const int* __restrict__ tmp, const int* __restrict__ bhs,
              int* __restrict__ offs, int* __restrict__ csr, int E, int N) {
    const int b = blockIdx.x;
    const int t = threadIdx.x;
    __shared__ int hist[128], excl[128], cur[128];
    const int bstart = bhs[b * NBLK];
    const int bend = (b + 1 < NB) ? bhs[(b + 1) * NBLK] : E;
    if (t < 128) hist[t] = 0;
    __syncthreads();
    for (int i = bstart + t; i < bend; i += 256)
        atomicAdd(&hist[tmp[i] & 127], 1);
    __syncthreads();
    if (t < 128) excl[t] = hist[t];
    __syncthreads();
    for (int o = 1; o < 128; o <<= 1) {
        int u = (t < 128 && t >= o) ? excl[t - o] : 0;
        __syncthreads();
        if (t < 128) excl[t] += u;
        __syncthreads();
    }
    const int node0 = b * 128;
    if (t < 128) {
        int base = bstart + ((t == 0) ? 0 : excl[t - 1]);
        if (node0 + t < N) offs[node0 + t] = base;
        cur[t] = base;
    }
    if (b == 0 && t == 0) offs[N] = E;
    __syncthreads();
    for (int i = bstart + t; i < bend; i += 256) {
        int e = tmp[i];
        int p = atomicAdd(&cur[e & 127], 1);
        csr[p] = e >> 7;
    }
}

// ------------------------- merged converts: x -> fp16, weights -> bf16 hi/lo
// W output is FRAGMENT-MAJOR: for 128-col mats, element (k,n) lands at
// ((w*8 + ks*2 + ct)*64 + quad*16 + m)*8 + j  where n = w*32+ct*16+m,
// k = ks*32 + quad*8 + j. A wave-load of one fragment is then a contiguous
// 1 KB read (lane = quad*16+m reads 16 B at lane*16) — R11's layout made
// every W load a 16-way line-split gather, the mlp bottleneck.
// W_h1 (64 cols): ((w*4 + ks)*64 + quad*16 + m)*8 + j, n = w*16+m.
// blocks [0, XB): xcvt (N*HID/4 = 1,600,000 float4 groups); [XB, XB+WB): wcvt.
#define XB 6250     // ceil(1600000/256)
#define WB 416      // ceil(106496/256)
__global__ __launch_bounds__(256)
void cvt_k(const float* __restrict__ x, _Float16* __restrict__ xh,
           const float* __restrict__ Wa, const float* __restrict__ Wb,
           const float* __restrict__ Wh1,
           unsigned short* __restrict__ whi, unsigned short* __restrict__ wlo) {
    if (blockIdx.x < XB) {
        int i = blockIdx.x * 256 + threadIdx.x;
        if (i < 1600000) {
            float4 v = *(const float4*)&x[i * 4];
            hv4 o;
            o.x = (_Float16)v.x; o.y = (_Float16)v.y;
            o.z = (_Float16)v.z; o.w = (_Float16)v.w;
            *(hv4*)&xh[i * 4] = o;
        }
        return;
    }
    int id = (blockIdx.x - XB) * 256 + threadIdx.x;
    float v; int dst;
    if (id < 98304) {                      // 3 x W_a then 3 x W_b (128x128)
        int isB = (id >= 49152);
        int id2 = isB ? id - 49152 : id;
        int l = id2 >> 14, e = id2 & 16383;
        v = isB ? Wb[id2] : Wa[id2];
        int k = e >> 7, n = e & 127;
        int w = n >> 5, ct = (n >> 4) & 1, m = n & 15;
        int ks = k >> 5, quad = (k >> 3) & 3, j = k & 7;
        int within = ((w * 8 + ks * 2 + ct) * 64 + quad * 16 + m) * 8 + j;
        dst = (2 * l + isB) * 16384 + within;
    } else if (id < 106496) {              // W_h1 [128][64]
        int e = id - 98304;
        v = Wh1[e];
        int k = e >> 6, n = e & 63;
        int w = n >> 4, m = n & 15;
        int ks = k >> 5, quad = (k >> 3) & 3, j = k & 7;
        dst = 6 * 16384 + ((w * 4 + ks) * 64 + quad * 16 + m) * 8 + j;
    } else return;
    unsigned short hi = f2bf(v);
    whi[dst] = hi;
    wlo[dst] = f2bf(v - bf2f(hi));
}

// ------------------------------------------- standalone gather-aggregate
// Pure gather kernel (no LDS, no phases): 16 nodes per 256-block, one
// quarter-wave (16 lanes x hv8 = full 256 B row) per node, unroll-4.
__global__ __launch_bounds__(256)
void agg16_k(const _Float16* __restrict__ h_in,
             const int* __restrict__ offs, const int* __restrict__ csr,
             const float* __restrict__ eps, int layer,
             _Float16* __restrict__ z) {
    const int qw = threadIdx.x >> 4;           // 0..15
    const int l16 = threadIdx.x & 15;
    const int node = blockIdx.x * 16 + qw;
    if (node >= N_NODES) return;
    const hv8* __restrict__ h8 = (const hv8*)h_in;   // row = 16 hv8
    const float sc = 1.0f + eps[layer];
    const int beg = offs[node], end = offs[node + 1];
    float a0[8] = {0,0,0,0,0,0,0,0};
    float a1[8] = {0,0,0,0,0,0,0,0};
    int j = beg;
    for (; j + 4 <= end; j += 4) {
        int s0 = csr[j], s1 = csr[j+1], s2 = csr[j+2], s3 = csr[j+3];
        hv8 v0 = h8[(size_t)s0 * 16 + l16];
        hv8 v1 = h8[(size_t)s1 * 16 + l16];
        hv8 v2 = h8[(size_t)s2 * 16 + l16];
        hv8 v3 = h8[(size_t)s3 * 16 + l16];
#pragma unroll
        for (int e = 0; e < 8; ++e) {
            a0[e] += (float)v0[e] + (float)v2[e];
            a1[e] += (float)v1[e] + (float)v3[e];
        }
    }
    for (; j < end; ++j) {
        hv8 v = h8[(size_t)csr[j] * 16 + l16];
#pragma unroll
        for (int e = 0; e < 8; ++e) a0[e] += (float)v[e];
    }
    hv8 self = h8[(size_t)node * 16 + l16];
    hv8 o;
#pragma unroll
    for (int e = 0; e < 8; ++e)
        o[e] = (_Float16)(sc * (float)self[e] + (a0[e] + a1[e]));
    ((hv8*)z)[(size_t)node * 16 + l16] = o;
}

// ------------------------------------------------------- MLP kernel (v3)
// One block = 64 rows (grid 782): halves the per-chip W traffic vs 32-row
// blocks and doubles MFMA per W load. W fragments in fragment-major layout
// (contiguous 1 KB wave-loads) and STREAMED per k-step (16 live regs).
// FP accumulate order per acc element unchanged (ks ascending).
// MFMA 16x16x32 layouts (verified R3): A[m=lane&15][k=quad*8+j],
// B fragment = per-lane value W[n][k] with n=...+m, k=quad*8+j (layout in cvt_k).
template <bool HEAD>
__global__ __launch_bounds__(256)
void mlp_k(const _Float16* __restrict__ z_in,
           const unsigned short* __restrict__ WAhi, const unsigned short* __restrict__ WAlo,
           const float* __restrict__ ba,
           const unsigned short* __restrict__ WBhi, const unsigned short* __restrict__ WBlo,
           const float* __restrict__ bb,
           const unsigned short* __restrict__ WHhi, const unsigned short* __restrict__ WHlo,
           const float* __restrict__ bh1,
           const float* __restrict__ W2, const float* __restrict__ b2,
           void* __restrict__ outp) {
    __shared__ unsigned short Zhi[64 * 136];   // 17,408 B
    __shared__ unsigned short Zlo[64 * 136];
    const int t = threadIdx.x;
    const int wave = t >> 6, lane = t & 63;
    const int m = lane & 15, quad = lane >> 4;
    const int row0 = blockIdx.x * 64;

    // ---------- stage z -> LDS bf16 hi/lo (coalesced hv8 reads)
    {
        const int quart = lane >> 4, l16 = lane & 15;
        const hv8* __restrict__ z8 = (const hv8*)z_in;
        for (int g = 0; g < 4; ++g) {
            const int r = wave * 16 + g * 4 + quart;
            const int node = row0 + r;
            float o[8] = {0,0,0,0,0,0,0,0};
            if (node < N_NODES) {
                hv8 v = z8[(size_t)node * 16 + l16];
#pragma unroll
                for (int e = 0; e < 8; ++e) o[e] = (float)v[e];
            }
            us4 hi0, hi1, lo0, lo1;
#pragma unroll
            for (int e = 0; e < 4; ++e) {
                hi0[e] = f2bf(o[e]);     lo0[e] = f2bf(o[e]     - bf2f(hi0[e]));
                hi1[e] = f2bf(o[e + 4]); lo1[e] = f2bf(o[e + 4] - bf2f(hi1[e]));
            }
            *(us4*)&Zhi[r * 136 + l16 * 8]     = hi0;
            *(us4*)&Zhi[r * 136 + l16 * 8 + 4] = hi1;
            *(us4*)&Zlo[r * 136 + l16 * 8]     = lo0;
            *(us4*)&Zlo[r * 136 + l16 * 8 + 4] = lo1;
        }
    }
    __syncthreads();

    // ---------- phase 2: z @ W_a (fragment-major W, streamed per ks)
    f32x4 acc[4][2];
    for (int s = 0; s < 4; ++s)
        for (int ct = 0; ct < 2; ++ct) acc[s][ct] = (f32x4){0, 0, 0, 0};
#pragma unroll 1
    for (int ks = 0; ks < 4; ++ks) {
        const int fA = (wave * 8 + ks * 2) * 512 + lane * 8;
        short8 wh0 = *(const short8*)&WAhi[fA];
        short8 wl0 = *(const short8*)&WAlo[fA];
        short8 wh1 = *(const short8*)&WAhi[fA + 512];
        short8 wl1 = *(const short8*)&WAlo[fA + 512];
        const int wo = ks * 32 + quad * 8;
#pragma unroll
        for (int s = 0; s < 4; ++s) {
            const int r = s * 16 + m;
            short8 zh = *(const short8*)&Zhi[r * 136 + wo];
            short8 zl = *(const short8*)&Zlo[r * 136 + wo];
            acc[s][0] = __builtin_amdgcn_mfma_f32_16x16x32_bf16(zh, wh0, acc[s][0], 0, 0, 0);
            acc[s][0] = __builtin_amdgcn_mfma_f32_16x16x32_bf16(zh, wl0, acc[s][0], 0, 0, 0);
            acc[s][0] = __builtin_amdgcn_mfma_f32_16x16x32_bf16(zl, wh0, acc[s][0], 0, 0, 0);
            acc[s][1] = __builtin_amdgcn_mfma_f32_16x16x32_bf16(zh, wh1, acc[s][1], 0, 0, 0);
            acc[s][1] = __builtin_amdgcn_mfma_f32_16x16x32_bf16(zh, wl1, acc[s][1], 0, 0, 0);
            acc[s][1] = __builtin_amdgcn_mfma_f32_16x16x32_bf16(zl, wh1, acc[s][1], 0, 0, 0);
        }
    }
    __syncthreads();   // all z reads done; safe to overwrite LDS

    // ---------- u = relu(acc + ba) -> LDS
    for (int s = 0; s < 4; ++s) {
        for (int ct = 0; ct < 2; ++ct) {
            int c = wave * 32 + ct * 16 + m;
            float bac = ba[c];
            for (int i = 0; i < 4; ++i) {
                int r = s * 16 + quad * 4 + i;
                float v = fmaxf(acc[s][ct][i] + bac, 0.0f);
                unsigned short hv = f2bf(v);
                Zhi[r * 136 + c] = hv;
                Zlo[r * 136 + c] = f2bf(v - bf2f(hv));
            }
        }
    }
    __syncthreads();

    // ---------- phase 3: u @ W_b
    for (int s = 0; s < 4; ++s)
        for (int ct = 0; ct < 2; ++ct) acc[s][ct] = (f32x4){0, 0, 0, 0};
#pragma unroll 1
    for (int ks = 0; ks < 4; ++ks) {
        const int fB = (wave * 8 + ks * 2) * 512 + lane * 8;
        short8 wh0 = *(const short8*)&WBhi[fB];
        short8 wl0 = *(const short8*)&WBlo[fB];
        short8 wh1 = *(const short8*)&WBhi[fB + 512];
        short8 wl1 = *(const short8*)&WBlo[fB + 512];
        const int wo = ks * 32 + quad * 8;
#pragma unroll
        for (int s = 0; s < 4; ++s) {
            const int r = s * 16 + m;
            short8 zh = *(const short8*)&Zhi[r * 136 + wo];
            short8 zl = *(const short8*)&Zlo[r * 136 + wo];
            acc[s][0] = __builtin_amdgcn_mfma_f32_16x16x32_bf16(zh, wh0, acc[s][0], 0, 0, 0);
            acc[s][0] = __builtin_amdgcn_mfma_f32_16x16x32_bf16(zh, wl0, acc[s][0], 0, 0, 0);
            acc[s][0] = __builtin_amdgcn_mfma_f32_16x16x32_bf16(zl, wh0, acc[s][0], 0, 0, 0);
            acc[s][1] = __builtin_amdgcn_mfma_f32_16x16x32_bf16(zh, wh1, acc[s][1], 0, 0, 0);
            acc[s][1] = __builtin_amdgcn_mfma_f32_16x16x32_bf16(zh, wl1, acc[s][1], 0, 0, 0);
            acc[s][1] = __builtin_amdgcn_mfma_f32_16x16x32_bf16(zl, wh1, acc[s][1], 0, 0, 0);
        }
    }

    if (!HEAD) {
        _Float16* hout = (_Float16*)outp;
        for (int s = 0; s < 4; ++s) {
            for (int ct = 0; ct < 2; ++ct) {
                int c = wave * 32 + ct * 16 + m;
                float bbc = bb[c];
                for (int i = 0; i < 4; ++i) {
                    int row = row0 + s * 16 + quad * 4 + i;
                    if (row < N_NODES)
                        hout[(size_t)row * 128 + c] = (_Float16)fmaxf(acc[s][ct][i] + bbc, 0.0f);
                }
            }
        }
    } else {
        __syncthreads();   // all u reads done; safe to overwrite LDS

        // ---------- h = relu(acc + bb) -> LDS
        for (int s = 0; s < 4; ++s) {
            for (int ct = 0; ct < 2; ++ct) {
                int c = wave * 32 + ct * 16 + m;
                float bbc = bb[c];
                for (int i = 0; i < 4; ++i) {
                    int r = s * 16 + quad * 4 + i;
                    float v = fmaxf(acc[s][ct][i] + bbc, 0.0f);
                    unsigned short hv = f2bf(v);
                    Zhi[r * 136 + c] = hv;
                    Zlo[r * 136 + c] = f2bf(v - bf2f(hv));
                }
            }
        }
        __syncthreads();

        // ---------- phase 4: h @ W_h1 (128 -> 64), fragment-major, streamed
        f32x4 a3[4];
        for (int s = 0; s < 4; ++s) a3[s] = (f32x4){0, 0, 0, 0};
#pragma unroll 1
        for (int ks = 0; ks < 4; ++ks) {
            const int fH = (wave * 4 + ks) * 512 + lane * 8;
            short8 hh = *(const short8*)&WHhi[fH];
            short8 hl = *(const short8*)&WHlo[fH];
            const int wo = ks * 32 + quad * 8;
#pragma unroll
            for (int s = 0; s < 4; ++s) {
                const int r = s * 16 + m;
                short8 zh = *(const short8*)&Zhi[r * 136 + wo];
                short8 zl = *(const short8*)&Zlo[r * 136 + wo];
                a3[s] = __builtin_amdgcn_mfma_f32_16x16x32_bf16(zh, hh, a3[s], 0, 0, 0);
                a3[s] = __builtin_amdgcn_mfma_f32_16x16x32_bf16(zh, hl, a3[s], 0, 0, 0);
                a3[s] = __builtin_amdgcn_mfma_f32_16x16x32_bf16(zl, hh, a3[s], 0, 0, 0);
            }
        }
        __syncthreads();   // phase-4 reads done; reuse LDS as fp32

        float* Hid = (float*)Zhi;   // 64 x 68 fp32 = 17,408 B (fits in Zhi)
        for (int s = 0; s < 4; ++s) {
            int c = wave * 16 + m;
            float bc = bh1[c];
            for (int i = 0; i < 4; ++i) {
                int r = s * 16 + quad * 4 + i;
                Hid[r * 68 + c] = fmaxf(a3[s][i] + bc, 0.0f);
            }
        }
        __syncthreads();

        // ---------- phase 5: hid @ W_h2 (64 -> 2) + b2 -> out
        // 256 threads: pair = t>>1 -> (r = pair>>1, col = pair&1), seg = t&1
        float* Red = (float*)Zlo;   // 256 floats (Zlo free after phase 4)
        {
            int pair = t >> 1, seg = t & 1;
            int r = pair >> 1, col = pair & 1;
            float p = 0.0f;
#pragma unroll
            for (int j = seg * 32; j < seg * 32 + 32; ++j)
                p += Hid[r * 68 + j] * W2[j * 2 + col];
            Red[t] = p;
        }
        __syncthreads();
        if (t < 128) {
            float* outF = (float*)outp;
            int r = t >> 1, col = t & 1;
            float a = b2[col] + (Red[t * 2] + Red[t * 2 + 1]);
            int node = row0 + r;
            if (node < N_NODES) outF[(size_t)node * 2 + col] = a;
        }
    }
}

// ------------------------------------------------------------------ launch

extern "C" void kernel_launch(void* const* d_in, const int* in_sizes, int n_in,
                              void* d_out, int out_size, void* d_ws, size_t ws_size,
                              hipStream_t stream) {
    const float* x    = (const float*)d_in[0];
    const int*   ei   = (const int*)d_in[1];
    const float* eps  = (const float*)d_in[2];
    const float* W_a  = (const float*)d_in[3];
    const float* b_a  = (const float*)d_in[4];
    const float* W_b  = (const float*)d_in[5];
    const float* b_b  = (const float*)d_in[6];
    const float* W_h1 = (const float*)d_in[7];
    const float* b_h1 = (const float*)d_in[8];
    const float* W_h2 = (const float*)d_in[9];
    const float* b_h2 = (const float*)d_in[10];
    float* out = (float*)d_out;

    const int N = N_NODES, E = N_EDGES;
    const int* src = ei;
    const int* dst = ei + E;

    char* ws = (char*)d_ws;
    size_t off = 0;
    auto carve = [&](size_t bytes) {
        char* p = ws + off;
        off = (off + bytes + 255) & ~(size_t)255;
        return p;
    };
    _Float16* xh   = (_Float16*)carve((size_t)N * HID * sizeof(_Float16));
    _Float16* zb   = (_Float16*)carve((size_t)N * HID * sizeof(_Float16));
    _Float16* bufA = (_Float16*)carve((size_t)N * HID * sizeof(_Float16));
    _Float16* bufB = (_Float16*)carve((size_t)N * HID * sizeof(_Float16));
    int*   tmp    = (int*)carve((size_t)E * sizeof(int));
    int*   csr    = (int*)carve((size_t)E * sizeof(int));
    int*   offs   = (int*)carve((size_t)(N + 1) * sizeof(int));
    int*   bh     = (int*)carve((size_t)NB * NBLK * sizeof(int));
    int*   bhs    = (int*)carve((size_t)NB * NBLK * sizeof(int));
    int*   bsum   = (int*)carve(64 * sizeof(int));
    unsigned short* whi = (unsigned short*)carve(7 * 16384 * sizeof(unsigned short));
    unsigned short* wlo = (unsigned short*)carve(7 * 16384 * sizeof(unsigned short));
    (void)ws_size;

    // ---- CSR build: streaming counting sort (LDS atomics only)
    const int M = NB * NBLK;                     // 62,560
    const int SB = (M + 2047) / 2048;            // 31 scan blocks
    hist_k<<<NBLK, 256, 0, stream>>>(dst, bh, E);
    scanA_k<<<SB, 256, 0, stream>>>(bh, bsum, M);
    scanC_k<<<SB, 256, 0, stream>>>(bh, bsum, bhs, M, SB);
    scatter_k<<<NBLK, 256, 0, stream>>>(src, dst, bhs, tmp, E);
    bucket_k<<<NB, 256, 0, stream>>>(tmp, bhs, offs, csr, E, N);

    // ---- merged input + weight conversion (fragment-major W)
    cvt_k<<<XB + WB, 256, 0, stream>>>(x, xh, W_a, W_b, W_h1, whi, wlo);

    const int agg_grid = (N + 15) / 16;
    const int mlp_grid = (N + 63) / 64;
    #define WSLOT(s) (whi + (s) * 16384), (wlo + (s) * 16384)
    #define NOHEAD (const unsigned short*)nullptr, (const unsigned short*)nullptr, \
                   (const float*)nullptr, (const float*)nullptr, (const float*)nullptr

    // layer 0
    agg16_k<<<agg_grid, 256, 0, stream>>>(xh, offs, csr, eps, 0, zb);
    mlp_k<false><<<mlp_grid, 256, 0, stream>>>(zb, WSLOT(0), b_a + 0 * 128,
        WSLOT(1), b_b + 0 * 128, NOHEAD, (void*)bufA);
    // layer 1
    agg16_k<<<agg_grid, 256, 0, stream>>>(bufA, offs, csr, eps, 1, zb);
    mlp_k<false><<<mlp_grid, 256, 0, stream>>>(zb, WSLOT(2), b_a + 1 * 128,
        WSLOT(3), b_b + 1 * 128, NOHEAD, (void*)bufB);
    // layer 2 + head
    agg16_k<<<agg_grid, 256, 0, stream>>>(bufB, offs, csr, eps, 2, zb);
    mlp_k<true><<<mlp_grid, 256, 0, stream>>>(zb, WSLOT(4), b_a + 2 * 128,
        WSLOT(5), b_b + 2 * 128, WSLOT(6), b_h1, W_h2, b_h2, (void*)out);
}